// Round 19
// baseline (245.267 us; speedup 1.0000x reference)
//
#include <hip/hip_runtime.h>
#include <cstdint>
#include <cstddef>

// ---------------------------------------------------------------------------
// Types / helpers
// ---------------------------------------------------------------------------
typedef short bf16x8 __attribute__((ext_vector_type(8)));
typedef short bf16x4 __attribute__((ext_vector_type(4)));
typedef float f32x4 __attribute__((ext_vector_type(4)));

#define D_MODEL 1024
#define SEQ     2048
#define NBATCH  2
#define NH      16
#define DKH     64
#define DFF     4096
#define MROWS   (NBATCH * SEQ)   // 4096

#if defined(__HIP_DEVICE_COMPILE__)
#if __has_builtin(__builtin_amdgcn_mfma_f32_16x16x16bf16_1k)
#define MFMA16(a, b, c) __builtin_amdgcn_mfma_f32_16x16x16bf16_1k(a, b, c, 0, 0, 0)
#else
#define MFMA16(a, b, c) __builtin_amdgcn_mfma_f32_16x16x16_bf16(a, b, c, 0, 0, 0)
#endif
#if __has_builtin(__builtin_amdgcn_exp2f)
#define EXP2(x) __builtin_amdgcn_exp2f(x)
#else
#define EXP2(x) exp2f(x)
#endif
#else
__device__ __host__ static inline f32x4 MFMA16(bf16x4, bf16x4, f32x4 c) {
  return c;
}
#define EXP2(x) exp2f(x)
#endif

__device__ __forceinline__ unsigned short f2bf(float f) {
  unsigned u = __builtin_bit_cast(unsigned, f);
  u += 0x7fffu + ((u >> 16) & 1u);          // round-to-nearest-even
  return (unsigned short)(u >> 16);
}
__device__ __forceinline__ float bf2f(unsigned short u) {
  return __builtin_bit_cast(float, (unsigned)u << 16);
}
__device__ __forceinline__ unsigned packbf2(float lo, float hi) {
  unsigned r;
  asm("v_cvt_pk_bf16_f32 %0, %1, %2" : "=v"(r) : "v"(lo), "v"(hi));
  return r;
}
__device__ __forceinline__ void gload_lds16(const void* g, void* l) {
  __builtin_amdgcn_global_load_lds(
      (const __attribute__((address_space(1))) unsigned*)g,
      (__attribute__((address_space(3))) unsigned*)l, 16, 0, 0);
}

// ---------------------------------------------------------------------------
// prep: blocks <4096 do LN1 (one row each, torch semantics); blocks >=4096 do
// weight cast f32->bf16 (dst: [wq 1M][wk 1M][wv 1M][wo 1M][w1 4M][w2 4M]) and
// mask -> float addend (0/-1e9).
// ---------------------------------------------------------------------------
__global__ __launch_bounds__(256) void prep_kernel(
    const float* __restrict__ x, const float* __restrict__ alpha,
    const float* __restrict__ beta, unsigned short* __restrict__ h1,
    const float* __restrict__ wq, const float* __restrict__ wk,
    const float* __restrict__ wv, const float* __restrict__ wo,
    const float* __restrict__ w1, const float* __restrict__ w2,
    const int* __restrict__ mask, unsigned short* __restrict__ dst,
    float* __restrict__ maskf) {
  const int t = threadIdx.x;
  if (blockIdx.x < MROWS) {
    // ---- LayerNorm row ----
    const int row = blockIdx.x;
    float4 v = *(const float4*)(x + (size_t)row * D_MODEL + t * 4);
    float s = v.x + v.y + v.z + v.w;
#pragma unroll
    for (int o = 1; o < 64; o <<= 1) s += __shfl_xor(s, o, 64);
    __shared__ float red[8];
    if ((t & 63) == 0) red[t >> 6] = s;
    __syncthreads();
    float mean = (red[0] + red[1] + red[2] + red[3]) * (1.f / D_MODEL);
    float dx = v.x - mean, dy = v.y - mean, dz = v.z - mean, dw = v.w - mean;
    float sq = dx * dx + dy * dy + dz * dz + dw * dw;
#pragma unroll
    for (int o = 1; o < 64; o <<= 1) sq += __shfl_xor(sq, o, 64);
    if ((t & 63) == 0) red[4 + (t >> 6)] = sq;
    __syncthreads();
    float var = (red[4] + red[5] + red[6] + red[7]) * (1.f / (D_MODEL - 1));
    float inv = 1.f / (sqrtf(var) + 1e-6f);
    float4 a = *(const float4*)(alpha + t * 4);
    float4 be = *(const float4*)(beta + t * 4);
    ushort4 o4;
    o4.x = f2bf(a.x * dx * inv + be.x);
    o4.y = f2bf(a.y * dy * inv + be.y);
    o4.z = f2bf(a.z * dz * inv + be.z);
    o4.w = f2bf(a.w * dw * inv + be.w);
    *(ushort4*)(h1 + (size_t)row * D_MODEL + t * 4) = o4;
  } else {
    // ---- weight cast + mask convert ----
    const int TOT4 = (12 << 20) >> 2;
    const int gid = (blockIdx.x - MROWS) * 256 + t;
    for (int i4 = gid; i4 < TOT4; i4 += 1024 * 256) {
      int i = i4 << 2;
      const float* src;
      int off;
      if (i < (4 << 20)) {
        src = (i < (2 << 20)) ? ((i < (1 << 20)) ? wq : wk)
                              : ((i < (3 << 20)) ? wv : wo);
        off = i & ((1 << 20) - 1);
      } else if (i < (8 << 20)) { src = w1; off = i - (4 << 20); }
      else                      { src = w2; off = i - (8 << 20); }
      float4 v = *(const float4*)(src + off);
      ushort4 o;
      o.x = f2bf(v.x); o.y = f2bf(v.y); o.z = f2bf(v.z); o.w = f2bf(v.w);
      *(ushort4*)(dst + i) = o;
    }
    if (gid < (NBATCH * SEQ / 4)) {
      int4 m = ((const int4*)mask)[gid];
      float4 f;
      f.x = (m.x == 0) ? -1e9f : 0.f;
      f.y = (m.y == 0) ? -1e9f : 0.f;
      f.z = (m.z == 0) ? -1e9f : 0.f;
      f.w = (m.w == 0) ? -1e9f : 0.f;
      ((float4*)maskf)[gid] = f;
    }
  }
}

// ---------------------------------------------------------------------------
// 256x256-tile 4-phase GEMM main-loop macro, fine-grained interleave
// (m201-style). Per K-tile T: {issue 2 gloads of T+1 -> vmcnt(2) -> barrier ->
// 4 x phase[8 ds_read_b128 ; 2 more gloads ; barrier ; setprio+16 MFMA ;
// barrier]}.  Requires locals: A, W, ldk, koff, m0, n0, srow, sch, wr, wc,
// g, c, Atile, Btile, acc, NT.
// ---------------------------------------------------------------------------
#define G256_STAGE1(T_, b_, i_)                                                    \
  {                                                                               \
    const int r_ = srow + (i_) * 64;                                              \
    gload_lds16(A + (size_t)(m0 + r_) * ldk + koff + (T_) * 64 +                  \
                    ((sch ^ (r_ & 7)) << 3),                                      \
                &Atile[b_][r_ * 64 + sch * 8]);                                   \
    gload_lds16(W + (size_t)(n0 + r_) * ldk + koff + (T_) * 64 +                  \
                    ((sch ^ (r_ & 7)) << 3),                                      \
                &Btile[b_][r_ * 64 + sch * 8]);                                   \
  }

#define G256_MAINLOOP()                                                           \
  G256_STAGE1(0, 0, 0); G256_STAGE1(0, 0, 1);                                     \
  G256_STAGE1(0, 0, 2); G256_STAGE1(0, 0, 3);                                     \
  for (int T = 0; T < NT; ++T) {                                                  \
    const int b = T & 1;                                                          \
    const bool more = (T + 1 < NT);                                               \
    if (more) {                                                                   \
      G256_STAGE1(T + 1, b ^ 1, 0);                                               \
      asm volatile("s_waitcnt vmcnt(2)" ::: "memory");                            \
    } else {                                                                      \
      asm volatile("s_waitcnt vmcnt(0)" ::: "memory");                            \
    }                                                                             \
    __builtin_amdgcn_sched_barrier(0);                                            \
    __builtin_amdgcn_s_barrier();                                                 \
    _Pragma("unroll") for (int q = 0; q < 4; ++q) {                               \
      const int kk = q >> 1, mh = (q & 1) * 4;                                    \
      bf16x8 af[4], bfq[4];                                                       \
      _Pragma("unroll") for (int j = 0; j < 4; j++) {                             \
        const int ar = wr * 128 + (mh + j) * 16 + c;                              \
        const int br = wc * 64 + j * 16 + c;                                      \
        const int sl = ((kk * 4 + g) ^ (c & 7)) << 3;                             \
        af[j] = *(const bf16x8*)&Atile[b][ar * 64 + sl];                          \
        bfq[j] = *(const bf16x8*)&Btile[b][br * 64 + sl];                         \
      }                                                                           \
      if (q > 0 && more) G256_STAGE1(T + 1, b ^ 1, q);                            \
      __builtin_amdgcn_s_barrier();                                               \
      __builtin_amdgcn_s_setprio(1);                                              \
      _Pragma("unroll") for (int j = 0; j < 4; j++)                               \
        _Pragma("unroll") for (int n = 0; n < 4; n++)                             \
          acc[mh + j][n] = __builtin_amdgcn_mfma_f32_16x16x32_bf16(               \
              af[j], bfq[n], acc[mh + j][n], 0, 0, 0);                            \
      __builtin_amdgcn_s_setprio(0);                                              \
      __builtin_amdgcn_s_barrier();                                               \
    }                                                                             \
  }

// FFN1 (RELU=1, full K) / FFN2 & proj (RELU=0, bf16 partials, split-K via
// blockIdx.z; per-block K chunk = KS).
template <int RELU>
__global__ __launch_bounds__(512, 2) void gemm256(
    const unsigned short* __restrict__ A, const unsigned short* __restrict__ W,
    const float* __restrict__ bias, unsigned short* __restrict__ out,
    int M, int N, int KS) {
  __shared__ unsigned short Atile[2][256 * 64];
  __shared__ unsigned short Btile[2][256 * 64];
  const int t = threadIdx.x, lane = t & 63, wid = t >> 6;
  const int g = lane >> 4, c = lane & 15;
  const int wr = wid >> 2, wc = wid & 3;          // 2x4 wave grid
  const int m0 = blockIdx.y * 256, n0 = blockIdx.x * 256;
  const int srow = t >> 3, sch = t & 7;           // staging row / 16B-chunk
  const int NT = KS >> 6;
  const int ldk = KS * gridDim.z;
  const int koff = blockIdx.z * KS;
  (void)M;

  f32x4 zero = {0.f, 0.f, 0.f, 0.f};
  f32x4 acc[8][4];
#pragma unroll
  for (int i = 0; i < 8; i++)
#pragma unroll
    for (int j = 0; j < 4; j++) acc[i][j] = zero;

  G256_MAINLOOP();

  float bv[4];
#pragma unroll
  for (int ni = 0; ni < 4; ni++)
    bv[ni] = RELU ? bias[n0 + wc * 64 + ni * 16 + c] : 0.f;

  unsigned short* po = out + (RELU ? 0 : (size_t)blockIdx.z * M * N);

#pragma unroll
  for (int mi = 0; mi < 8; mi++) {
#pragma unroll
    for (int ni = 0; ni < 4; ni++) {
      const int mb = m0 + wr * 128 + mi * 16 + g * 4;
      const int n = n0 + wc * 64 + ni * 16 + c;
#pragma unroll
      for (int r = 0; r < 4; r++) {
        float v = acc[mi][ni][r] + bv[ni];
        if (RELU) v = fmaxf(v, 0.f);
        po[(size_t)(mb + r) * N + n] = f2bf(v);
      }
    }
  }
}

// QKV on the 256-tile structure: grid (4, 16, 3); blockIdx.z selects weight.
// Q written pre-scaled by 1/8; K plain; V written transposed Vt (B,H,dk,S).
__global__ __launch_bounds__(512, 2) void gemm256_qkv(
    const unsigned short* __restrict__ A, const unsigned short* __restrict__ Wbase,
    const float* __restrict__ bq, const float* __restrict__ bk,
    const float* __restrict__ bv_, unsigned short* __restrict__ qkout,
    unsigned short* __restrict__ vtout) {
  __shared__ unsigned short Atile[2][256 * 64];
  __shared__ unsigned short Btile[2][256 * 64];
  const int t = threadIdx.x, lane = t & 63, wid = t >> 6;
  const int g = lane >> 4, c = lane & 15;
  const int wr = wid >> 2, wc = wid & 3;
  const int m0 = blockIdx.y * 256, n0 = blockIdx.x * 256;
  const int srow = t >> 3, sch = t & 7;
  const int NT = 16;                              // K = 1024
  const int ldk = 1024, koff = 0;
  const int wsel = blockIdx.z;
  const unsigned short* W = Wbase + ((size_t)wsel << 20);
  const float* bias = (wsel == 0) ? bq : (wsel == 1) ? bk : bv_;

  f32x4 zero = {0.f, 0.f, 0.f, 0.f};
  f32x4 acc[8][4];
#pragma unroll
  for (int i = 0; i < 8; i++)
#pragma unroll
    for (int j = 0; j < 4; j++) acc[i][j] = zero;

  G256_MAINLOOP();

  float bvv[4];
#pragma unroll
  for (int ni = 0; ni < 4; ni++) bvv[ni] = bias[n0 + wc * 64 + ni * 16 + c];
  const float qsc = (wsel == 0) ? 0.125f : 1.f;

  if (wsel < 2) {
    unsigned short* outp = qkout + ((size_t)wsel << 22);  // q then k
#pragma unroll
    for (int mi = 0; mi < 8; mi++) {
#pragma unroll
      for (int ni = 0; ni < 4; ni++) {
        const int mb = m0 + wr * 128 + mi * 16 + g * 4;
        const int n = n0 + wc * 64 + ni * 16 + c;
#pragma unroll
        for (int r = 0; r < 4; r++)
          outp[(size_t)(mb + r) * 1024 + n] = f2bf((acc[mi][ni][r] + bvv[ni]) * qsc);
      }
    }
  } else {
    // V^T: vtout[(b*1024 + n)*2048 + s]; mb%4==0 so 4 r-values share b
#pragma unroll
    for (int mi = 0; mi < 8; mi++) {
#pragma unroll
      for (int ni = 0; ni < 4; ni++) {
        const int mb = m0 + wr * 128 + mi * 16 + g * 4;
        const int n = n0 + wc * 64 + ni * 16 + c;
        const int b = mb >> 11, s2 = mb & 2047;
        ushort4 o4;
        o4.x = f2bf(acc[mi][ni][0] + bvv[ni]);
        o4.y = f2bf(acc[mi][ni][1] + bvv[ni]);
        o4.z = f2bf(acc[mi][ni][2] + bvv[ni]);
        o4.w = f2bf(acc[mi][ni][3] + bvv[ni]);
        *(ushort4*)(vtout + ((size_t)(b * 1024 + n)) * 2048 + s2) = o4;
      }
    }
  }
}

// ---------------------------------------------------------------------------
// Flash attention, 8-wave blocks (proven round-15 version). grid = (B*H, S/128).
// ---------------------------------------------------------------------------
#define ATTN_STAGE64(base_, buf_)                                                   \
  {                                                                                 \
    const int r_ = t >> 3, ch_ = t & 7;                                             \
    gload_lds16(Kb + (size_t)((base_) + r_) * D_MODEL + ((ch_ ^ (r_ & 7)) << 3),    \
                &Klds[buf_][t * 8]);                                                \
    gload_lds16(Vb + (size_t)r_ * SEQ + (base_) + ((ch_ ^ (r_ & 7)) << 3),          \
                &Vlds[buf_][t * 8]);                                                \
  }

__global__ __launch_bounds__(512, 4) void attn_kernel(
    const unsigned short* __restrict__ Q, const unsigned short* __restrict__ Kmat,
    const unsigned short* __restrict__ Vt, const float* __restrict__ maskf,
    unsigned short* __restrict__ O) {
  __shared__ unsigned short Klds[2][64 * 64];
  __shared__ unsigned short Vlds[2][64 * 64];
  __shared__ float masklds[SEQ];
  const int t = threadIdx.x, lane = t & 63, wid = t >> 6;
  const int g = lane >> 4, c = lane & 15;
  const int bh = blockIdx.x, qt = blockIdx.y;   // bh on x => XCD = bh%8
  const int b = bh >> 4, h = bh & 15;
  const int q0 = qt * 128 + wid * 16;           // 8 waves x 16 q-rows

  const unsigned short* Qb = Q + (size_t)b * SEQ * D_MODEL + h * DKH;
  const unsigned short* Kb = Kmat + (size_t)b * SEQ * D_MODEL + h * DKH;
  const unsigned short* Vb = Vt + (size_t)bh * DKH * SEQ;
  const float* mbf = maskf + b * SEQ;

  bf16x8 qf[2];
#pragma unroll
  for (int kd = 0; kd < 2; kd++)
    qf[kd] = *(const bf16x8*)&Qb[(size_t)(q0 + c) * D_MODEL + kd * 32 + g * 8];

  f32x4 zero = {0.f, 0.f, 0.f, 0.f};
  f32x4 of[4];
#pragma unroll
  for (int j = 0; j < 4; j++) of[j] = zero;
  float mrun = -1e30f, lrun = 0.f;

  // stage mask addends (2048 floats = 8 KB, one gload/thread) + first K/V tile
  gload_lds16(mbf + t * 4, &masklds[t * 4]);
  ATTN_STAGE64(0, 0);

  for (int kv = 0; kv < 32; ++kv) {
    const int buf = kv & 1;
    const int base = kv * 64;
    __syncthreads();                        // drains this buf's gloads
    if (kv < 31) ATTN_STAGE64(base + 64, buf ^ 1);

    // --- QK^T: S^T[kv 64][q 16] per wave ---
    f32x4 sf[4];
    {
      bf16x8 kf0[4], kf1[4];
#pragma unroll
      for (int nb = 0; nb < 4; nb++) {
        const int row = nb * 16 + c;
        kf0[nb] = *(const bf16x8*)&Klds[buf][row * 64 + ((g ^ (c & 7)) << 3)];
        kf1[nb] = *(const bf16x8*)&Klds[buf][row * 64 + (((4 + g) ^ (c & 7)) << 3)];
      }
      __builtin_amdgcn_s_setprio(1);
#pragma unroll
      for (int nb = 0; nb < 4; nb++) {
        f32x4 s = zero;
        s = __builtin_amdgcn_mfma_f32_16x16x32_bf16(kf0[nb], qf[0], s, 0, 0, 0);
        s = __builtin_amdgcn_mfma_f32_16x16x32_bf16(kf1[nb], qf[1], s, 0, 0, 0);
        sf[nb] = s;
      }
      __builtin_amdgcn_s_setprio(0);
    }

    // additive mask (pre-converted 0/-1e9)
#pragma unroll
    for (int nb = 0; nb < 4; nb++) {
      float4 ma = *(const float4*)&masklds[base + nb * 16 + g * 4];
      sf[nb][0] += ma.x; sf[nb][1] += ma.y; sf[nb][2] += ma.z; sf[nb][3] += ma.w;
    }

    // online softmax with defer-max (THR=8)
    float pm = -1e30f;
#pragma unroll
    for (int nb = 0; nb < 4; nb++)
#pragma unroll
      for (int r = 0; r < 4; r++) pm = fmaxf(pm, sf[nb][r]);
    pm = fmaxf(pm, __shfl_xor(pm, 16, 64));
    pm = fmaxf(pm, __shfl_xor(pm, 32, 64));
    if (!__all(pm <= mrun + 8.f)) {
      float mnew = fmaxf(mrun, pm);
      float fsc = EXP2((mrun - mnew) * 1.44269504f);
      lrun *= fsc;
#pragma unroll
      for (int dkb = 0; dkb < 4; dkb++) of[dkb] *= fsc;
      mrun = mnew;
    }
    const float mb2 = mrun * 1.44269504f;
    float ps = 0.f;
#pragma unroll
    for (int nb = 0; nb < 4; nb++)
#pragma unroll
      for (int r = 0; r < 4; r++) {
        float p = EXP2(fmaf(sf[nb][r], 1.44269504f, -mb2));
        sf[nb][r] = p;
        ps += p;
      }
    lrun += ps;

    // --- PV: of[dkb] += V^T-frag x P^T-frag per 16-kv block nb.
#pragma unroll
    for (int nb = 0; nb < 4; nb++) {
      bf16x4 vv[4];
#pragma unroll
      for (int dkb = 0; dkb < 4; dkb++) {
        const int row = dkb * 16 + c;
        const int vbyte = row * 128 + ((((nb << 1) + (g >> 1)) ^ (c & 7)) << 4) +
                          ((g & 1) << 3);
        vv[dkb] = *(const bf16x4*)((const char*)Vlds[buf] + vbyte);
      }
      unsigned plo = packbf2(sf[nb][0], sf[nb][1]);
      unsigned phi = packbf2(sf[nb][2], sf[nb][3]);
      unsigned long long uu = (unsigned long long)plo |
                              ((unsigned long long)phi << 32);
      bf16x4 pf = __builtin_bit_cast(bf16x4, uu);
      __builtin_amdgcn_s_setprio(1);
#pragma unroll
      for (int dkb = 0; dkb < 4; dkb++)
        of[dkb] = MFMA16(vv[dkb], pf, of[dkb]);
      __builtin_amdgcn_s_setprio(0);
    }
  }

  float lt = lrun;
  lt += __shfl_xor(lt, 16, 64);
  lt += __shfl_xor(lt, 32, 64);
  float inv = 1.f / lt;
#pragma unroll
  for (int dkb = 0; dkb < 4; dkb++) {
    ushort4 o4;
    o4.x = f2bf(of[dkb][0] * inv);
    o4.y = f2bf(of[dkb][1] * inv);
    o4.z = f2bf(of[dkb][2] * inv);
    o4.w = f2bf(of[dkb][3] * inv);
    *(ushort4*)&O[(size_t)(b * SEQ + q0 + c) * D_MODEL + h * DKH + dkb * 16 +
                  g * 4] = o4;
  }
}

// ---------------------------------------------------------------------------
// Fused epilogues (bf16 split-K partials)
// proj_ln2: x2 = x + P0..P3 + bo;  h2 = LN2(x2).  one block per row.
// ---------------------------------------------------------------------------
__global__ __launch_bounds__(256) void proj_ln2_kernel(
    const float* __restrict__ x, const unsigned short* __restrict__ P0,
    const float* __restrict__ bo, const float* __restrict__ alpha,
    const float* __restrict__ beta, float* __restrict__ x2,
    unsigned short* __restrict__ h2) {
  const int row = blockIdx.x;
  const int t = threadIdx.x;
  const size_t idx = (size_t)row * D_MODEL + t * 4;
  const size_t stride = (size_t)MROWS * D_MODEL;
  float4 xv = *(const float4*)(x + idx);
  ushort4 p0u = *(const ushort4*)(P0 + idx);
  ushort4 p1u = *(const ushort4*)(P0 + stride + idx);
  ushort4 p2u = *(const ushort4*)(P0 + 2 * stride + idx);
  ushort4 p3u = *(const ushort4*)(P0 + 3 * stride + idx);
  float4 bo4 = *(const float4*)(bo + t * 4);
  float4 v;
  v.x = xv.x + (bf2f(p0u.x) + bf2f(p1u.x)) + (bf2f(p2u.x) + bf2f(p3u.x)) + bo4.x;
  v.y = xv.y + (bf2f(p0u.y) + bf2f(p1u.y)) + (bf2f(p2u.y) + bf2f(p3u.y)) + bo4.y;
  v.z = xv.z + (bf2f(p0u.z) + bf2f(p1u.z)) + (bf2f(p2u.z) + bf2f(p3u.z)) + bo4.z;
  v.w = xv.w + (bf2f(p0u.w) + bf2f(p1u.w)) + (bf2f(p2u.w) + bf2f(p3u.w)) + bo4.w;
  *(float4*)(x2 + idx) = v;

  float s = v.x + v.y + v.z + v.w;
#pragma unroll
  for (int o = 1; o < 64; o <<= 1) s += __shfl_xor(s, o, 64);
  __shared__ float red[8];
  if ((t & 63) == 0) red[t >> 6] = s;
  __syncthreads();
  float mean = (red[0] + red[1] + red[2] + red[3]) * (1.f / D_MODEL);
  float dx = v.x - mean, dy = v.y - mean, dz = v.z - mean, dw = v.w - mean;
  float sq = dx * dx + dy * dy + dz * dz + dw * dw;
#pragma unroll
  for (int o = 1; o < 64; o <<= 1) sq += __shfl_xor(sq, o, 64);
  if ((t & 63) == 0) red[4 + (t >> 6)] = sq;
  __syncthreads();
  float var = (red[4] + red[5] + red[6] + red[7]) * (1.f / (D_MODEL - 1));
  float inv = 1.f / (sqrtf(var) + 1e-6f);
  float4 a = *(const float4*)(alpha + t * 4);
  float4 be = *(const float4*)(beta + t * 4);
  ushort4 o4;
  o4.x = f2bf(a.x * dx * inv + be.x);
  o4.y = f2bf(a.y * dy * inv + be.y);
  o4.z = f2bf(a.z * dz * inv + be.z);
  o4.w = f2bf(a.w * dw * inv + be.w);
  *(ushort4*)(h2 + idx) = o4;
}

// ffn2_add: out = x2 + Q0+Q1+Q2+Q3 + b2  (final output, f32; bf16 partials x4)
__global__ __launch_bounds__(256) void ffn2_add_kernel(
    const float* __restrict__ x2, const unsigned short* __restrict__ Q0,
    const float* __restrict__ b2, float* __restrict__ out) {
  const int i4 = blockIdx.x * blockDim.x + threadIdx.x;  // 1M float4s
  const size_t idx = (size_t)i4 * 4;
  const size_t stride = (size_t)MROWS * D_MODEL;
  float4 a = *(const float4*)(x2 + idx);
  ushort4 q0u = *(const ushort4*)(Q0 + idx);
  ushort4 q1u = *(const ushort4*)(Q0 + stride + idx);
  ushort4 q2u = *(const ushort4*)(Q0 + 2 * stride + idx);
  ushort4 q3u = *(const ushort4*)(Q0 + 3 * stride + idx);
  float4 b = *(const float4*)(b2 + ((i4 & 255) * 4));
  float4 v;
  v.x = a.x + (bf2f(q0u.x) + bf2f(q1u.x)) + (bf2f(q2u.x) + bf2f(q3u.x)) + b.x;
  v.y = a.y + (bf2f(q0u.y) + bf2f(q1u.y)) + (bf2f(q2u.y) + bf2f(q3u.y)) + b.y;
  v.z = a.z + (bf2f(q0u.z) + bf2f(q1u.z)) + (bf2f(q2u.z) + bf2f(q3u.z)) + b.z;
  v.w = a.w + (bf2f(q0u.w) + bf2f(q1u.w)) + (bf2f(q2u.w) + bf2f(q3u.w)) + b.w;
  *(float4*)(out + idx) = v;
}

// ---------------------------------------------------------------------------
// Launch
// ---------------------------------------------------------------------------
extern "C" void kernel_launch(void* const* d_in, const int* in_sizes, int n_in,
                              void* d_out, int out_size, void* d_ws, size_t ws_size,
                              hipStream_t stream) {
  (void)in_sizes; (void)n_in; (void)out_size; (void)ws_size;
  const float* x    = (const float*)d_in[0];
  const int*   mask = (const int*)d_in[1];
  const float* wq   = (const float*)d_in[2];
  const float* bq   = (const float*)d_in[3];
  const float* wk   = (const float*)d_in[4];
  const float* bk   = (const float*)d_in[5];
  const float* wv   = (const float*)d_in[6];
  const float* bv   = (const float*)d_in[7];
  const float* wo   = (const float*)d_in[8];
  const float* bo   = (const float*)d_in[9];
  const float* w1   = (const float*)d_in[10];
  const float* b1   = (const float*)d_in[11];
  const float* w2   = (const float*)d_in[12];
  const float* b2   = (const float*)d_in[13];
  const float* ln1a = (const float*)d_in[14];
  const float* ln1b = (const float*)d_in[15];
  const float* ln2a = (const float*)d_in[16];
  const float* ln2b = (const float*)d_in[17];

  char* ws = (char*)d_ws;
  unsigned short* w_bf  = (unsigned short*)ws;            // 24 MB bf16 weights
  unsigned short* wq_bf = w_bf;
  unsigned short* wo_bf = w_bf + (3u << 20);
  unsigned short* w1_bf = w_bf + (4u << 20);
  unsigned short* w2_bf = w_bf + (8u << 20);
  unsigned short* h1    = (unsigned short*)(ws + (24u << 20));
  unsigned short* qbuf  = (unsigned short*)(ws + (32u << 20));
  unsigned short* kbuf  = (unsigned short*)(ws + (40u << 20));
  unsigned short* vtbuf = (unsigned short*)(ws + (48u << 20));
  unsigned short* attnb = (unsigned short*)(ws + (56u << 20));
  float*          x2    = (float*)(ws + (64u << 20));     // 16 MB
  unsigned short* h2    = (unsigned short*)(ws + (80u << 20));
  unsigned short* ffn1  = (unsigned short*)(ws + (88u << 20));  // 32 MB -> 120
  unsigned short* pp    = (unsigned short*)(ws + (88u << 20)); // proj partials
                                                          // (4x8MB = 88..120MB,
                                                          // dead before ffn1)
  unsigned short* qq    = (unsigned short*)(ws + (24u << 20)); // ffn2 partials
                                                          // (4x8MB = 24..56MB;
                                                          // h1..attnb dead)
  float*          maskf = (float*)(ws + (120u << 20));    // 16 KB

  prep_kernel<<<MROWS + 1024, 256, 0, stream>>>(
      x, ln1a, ln1b, h1, wq, wk, wv, wo, w1, w2, mask, w_bf, maskf);
  gemm256_qkv<<<dim3(4, 16, 3), 512, 0, stream>>>(
      h1, wq_bf, bq, bk, bv, qbuf, vtbuf);
  attn_kernel<<<dim3(32, 16), 512, 0, stream>>>(qbuf, kbuf, vtbuf, maskf, attnb);
  gemm256<0><<<dim3(4, 16, 4), 512, 0, stream>>>(
      attnb, wo_bf, nullptr, pp, MROWS, D_MODEL, 256);
  proj_ln2_kernel<<<MROWS, 256, 0, stream>>>(
      x, pp, bo, ln2a, ln2b, x2, h2);
  gemm256<1><<<dim3(16, 16), 512, 0, stream>>>(
      h2, w1_bf, b1, ffn1, MROWS, DFF, D_MODEL);
  gemm256<0><<<dim3(4, 16, 4), 512, 0, stream>>>(
      ffn1, w2_bf, nullptr, qq, MROWS, D_MODEL, 1024);
  ffn2_add_kernel<<<4096, 256, 0, stream>>>(x2, qq, b2, (float*)d_out);
}

// Round 20
// 242.171 us; speedup vs baseline: 1.0128x; 1.0128x over previous
//
#include <hip/hip_runtime.h>
#include <cstdint>
#include <cstddef>

// ---------------------------------------------------------------------------
// Types / helpers
// ---------------------------------------------------------------------------
typedef short bf16x8 __attribute__((ext_vector_type(8)));
typedef short bf16x4 __attribute__((ext_vector_type(4)));
typedef float f32x4 __attribute__((ext_vector_type(4)));

#define D_MODEL 1024
#define SEQ     2048
#define NBATCH  2
#define NH      16
#define DKH     64
#define DFF     4096
#define MROWS   (NBATCH * SEQ)   // 4096

#if defined(__HIP_DEVICE_COMPILE__)
#if __has_builtin(__builtin_amdgcn_mfma_f32_16x16x16bf16_1k)
#define MFMA16(a, b, c) __builtin_amdgcn_mfma_f32_16x16x16bf16_1k(a, b, c, 0, 0, 0)
#else
#define MFMA16(a, b, c) __builtin_amdgcn_mfma_f32_16x16x16_bf16(a, b, c, 0, 0, 0)
#endif
#if __has_builtin(__builtin_amdgcn_exp2f)
#define EXP2(x) __builtin_amdgcn_exp2f(x)
#else
#define EXP2(x) exp2f(x)
#endif
#else
__device__ __host__ static inline f32x4 MFMA16(bf16x4, bf16x4, f32x4 c) {
  return c;
}
#define EXP2(x) exp2f(x)
#endif

__device__ __forceinline__ unsigned short f2bf(float f) {
  unsigned u = __builtin_bit_cast(unsigned, f);
  u += 0x7fffu + ((u >> 16) & 1u);          // round-to-nearest-even
  return (unsigned short)(u >> 16);
}
__device__ __forceinline__ float bf2f(unsigned short u) {
  return __builtin_bit_cast(float, (unsigned)u << 16);
}
__device__ __forceinline__ unsigned packbf2(float lo, float hi) {
  unsigned r;
  asm("v_cvt_pk_bf16_f32 %0, %1, %2" : "=v"(r) : "v"(lo), "v"(hi));
  return r;
}
__device__ __forceinline__ void gload_lds16(const void* g, void* l) {
  __builtin_amdgcn_global_load_lds(
      (const __attribute__((address_space(1))) unsigned*)g,
      (__attribute__((address_space(3))) unsigned*)l, 16, 0, 0);
}

// ---------------------------------------------------------------------------
// prep: blocks <4096 do LN1 (one row each, torch semantics); blocks >=4096 do
// weight cast f32->bf16 (dst: [wq 1M][wk 1M][wv 1M][wo 1M][w1 4M][w2 4M]) and
// mask -> float addend (0/-1e9).
// ---------------------------------------------------------------------------
__global__ __launch_bounds__(256) void prep_kernel(
    const float* __restrict__ x, const float* __restrict__ alpha,
    const float* __restrict__ beta, unsigned short* __restrict__ h1,
    const float* __restrict__ wq, const float* __restrict__ wk,
    const float* __restrict__ wv, const float* __restrict__ wo,
    const float* __restrict__ w1, const float* __restrict__ w2,
    const int* __restrict__ mask, unsigned short* __restrict__ dst,
    float* __restrict__ maskf) {
  const int t = threadIdx.x;
  if (blockIdx.x < MROWS) {
    // ---- LayerNorm row ----
    const int row = blockIdx.x;
    float4 v = *(const float4*)(x + (size_t)row * D_MODEL + t * 4);
    float s = v.x + v.y + v.z + v.w;
#pragma unroll
    for (int o = 1; o < 64; o <<= 1) s += __shfl_xor(s, o, 64);
    __shared__ float red[8];
    if ((t & 63) == 0) red[t >> 6] = s;
    __syncthreads();
    float mean = (red[0] + red[1] + red[2] + red[3]) * (1.f / D_MODEL);
    float dx = v.x - mean, dy = v.y - mean, dz = v.z - mean, dw = v.w - mean;
    float sq = dx * dx + dy * dy + dz * dz + dw * dw;
#pragma unroll
    for (int o = 1; o < 64; o <<= 1) sq += __shfl_xor(sq, o, 64);
    if ((t & 63) == 0) red[4 + (t >> 6)] = sq;
    __syncthreads();
    float var = (red[4] + red[5] + red[6] + red[7]) * (1.f / (D_MODEL - 1));
    float inv = 1.f / (sqrtf(var) + 1e-6f);
    float4 a = *(const float4*)(alpha + t * 4);
    float4 be = *(const float4*)(beta + t * 4);
    ushort4 o4;
    o4.x = f2bf(a.x * dx * inv + be.x);
    o4.y = f2bf(a.y * dy * inv + be.y);
    o4.z = f2bf(a.z * dz * inv + be.z);
    o4.w = f2bf(a.w * dw * inv + be.w);
    *(ushort4*)(h1 + (size_t)row * D_MODEL + t * 4) = o4;
  } else {
    // ---- weight cast + mask convert ----
    const int TOT4 = (12 << 20) >> 2;
    const int gid = (blockIdx.x - MROWS) * 256 + t;
    for (int i4 = gid; i4 < TOT4; i4 += 1024 * 256) {
      int i = i4 << 2;
      const float* src;
      int off;
      if (i < (4 << 20)) {
        src = (i < (2 << 20)) ? ((i < (1 << 20)) ? wq : wk)
                              : ((i < (3 << 20)) ? wv : wo);
        off = i & ((1 << 20) - 1);
      } else if (i < (8 << 20)) { src = w1; off = i - (4 << 20); }
      else                      { src = w2; off = i - (8 << 20); }
      float4 v = *(const float4*)(src + off);
      ushort4 o;
      o.x = f2bf(v.x); o.y = f2bf(v.y); o.z = f2bf(v.z); o.w = f2bf(v.w);
      *(ushort4*)(dst + i) = o;
    }
    if (gid < (NBATCH * SEQ / 4)) {
      int4 m = ((const int4*)mask)[gid];
      float4 f;
      f.x = (m.x == 0) ? -1e9f : 0.f;
      f.y = (m.y == 0) ? -1e9f : 0.f;
      f.z = (m.z == 0) ? -1e9f : 0.f;
      f.w = (m.w == 0) ? -1e9f : 0.f;
      ((float4*)maskf)[gid] = f;
    }
  }
}

// ---------------------------------------------------------------------------
// GEMM core macros (128x128 tile, BK=32, 4 waves 2x2, double-buffered LDS)
// ---------------------------------------------------------------------------
#define GEMM_STAGE(A_, W_, LD_, koff_, kt_, buf_)                                  \
  {                                                                                \
    int ke_ = (koff_) + (kt_) * 32;                                                \
    gload_lds16(A_ + (size_t)(m0 + srow) * (LD_) + ke_ + sce, &lds[(buf_)][0][t * 8]);        \
    gload_lds16(A_ + (size_t)(m0 + 64 + srow) * (LD_) + ke_ + sce, &lds[(buf_)][0][2048 + t * 8]); \
    gload_lds16(W_ + (size_t)(n0 + srow) * (LD_) + ke_ + sce, &lds[(buf_)][1][t * 8]);        \
    gload_lds16(W_ + (size_t)(n0 + 64 + srow) * (LD_) + ke_ + sce, &lds[(buf_)][1][2048 + t * 8]); \
  }

#define GEMM_MAINLOOP(A_, W_, LD_, K_, koff_)                                      \
  GEMM_STAGE(A_, W_, LD_, koff_, 0, 0);                                            \
  for (int kt = 0; kt < ((K_) >> 5); ++kt) {                                       \
    __syncthreads();                                                               \
    if (kt + 1 < ((K_) >> 5)) GEMM_STAGE(A_, W_, LD_, koff_, kt + 1, (kt + 1) & 1); \
    const unsigned short* la = lds[kt & 1][0];                                     \
    const unsigned short* lb = lds[kt & 1][1];                                     \
    bf16x8 af[4], bfr[4];                                                          \
    _Pragma("unroll") for (int i = 0; i < 4; i++) {                                \
      af[i]  = *(const bf16x8*)&la[(wm + i * 16 + c) * 32 + g * 8];                \
      bfr[i] = *(const bf16x8*)&lb[(wn + i * 16 + c) * 32 + g * 8];                \
    }                                                                              \
    _Pragma("unroll") for (int mi = 0; mi < 4; mi++)                               \
      _Pragma("unroll") for (int ni = 0; ni < 4; ni++)                             \
        acc[mi][ni] = __builtin_amdgcn_mfma_f32_16x16x32_bf16(af[mi], bfr[ni],     \
                                                              acc[mi][ni], 0, 0, 0); \
  }

enum { MODE_BF16 = 0, MODE_RELU = 2, MODE_PARTIAL = 4 };

template <int MODE>
__global__ __launch_bounds__(256) void gemm_bt(
    const unsigned short* __restrict__ A, const unsigned short* __restrict__ W,
    const float* __restrict__ bias, void* __restrict__ outp, int M, int N, int K) {
  __shared__ unsigned short lds[2][2][128 * 32];
  const int t = threadIdx.x;
  const int lane = t & 63, wid = t >> 6;
  const int g = lane >> 4, c = lane & 15;
  const int m0 = blockIdx.y * 128, n0 = blockIdx.x * 128;
  const int wm = (wid >> 1) * 64, wn = (wid & 1) * 64;
  const int srow = t >> 2, sce = (t & 3) * 8;
  const int ldk = K * gridDim.z;
  const int koff = blockIdx.z * K;

  f32x4 zero = {0.f, 0.f, 0.f, 0.f};
  f32x4 acc[4][4];
#pragma unroll
  for (int i = 0; i < 4; i++)
#pragma unroll
    for (int j = 0; j < 4; j++) acc[i][j] = zero;

  GEMM_MAINLOOP(A, W, ldk, K, koff);

  float bv[4];
#pragma unroll
  for (int ni = 0; ni < 4; ni++)
    bv[ni] = (MODE == MODE_PARTIAL) ? 0.f : bias[n0 + wn + ni * 16 + c];

  unsigned short* po = (unsigned short*)outp +
                       ((MODE == MODE_PARTIAL) ? (size_t)blockIdx.z * M * N : 0);

#pragma unroll
  for (int mi = 0; mi < 4; mi++) {
#pragma unroll
    for (int ni = 0; ni < 4; ni++) {
      const int mb = m0 + wm + mi * 16 + g * 4;
      const int n = n0 + wn + ni * 16 + c;
#pragma unroll
      for (int r = 0; r < 4; r++) {
        const int m = mb + r;
        float v = acc[mi][ni][r] + bv[ni];
        if (MODE == MODE_RELU) v = fmaxf(v, 0.f);
        po[(size_t)m * N + n] = f2bf(v);   // bf16 partials / outputs
      }
    }
  }
}

// ---------------------------------------------------------------------------
// 256x256-tile 4-phase GEMM main-loop macro, fine-grained interleave
// (m201-style). Per K-tile T: {issue 2 gloads of T+1 -> vmcnt(2) -> barrier ->
// 4 x phase[8 ds_read_b128 ; 2 more gloads ; barrier ; setprio+16 MFMA ;
// barrier]}.  Requires locals: A, W, ldk, koff, m0, n0, srow, sch, wr, wc,
// g, c, Atile, Btile, acc, NT.
// ---------------------------------------------------------------------------
#define G256_STAGE1(T_, b_, i_)                                                    \
  {                                                                               \
    const int r_ = srow + (i_) * 64;                                              \
    gload_lds16(A + (size_t)(m0 + r_) * ldk + koff + (T_) * 64 +                  \
                    ((sch ^ (r_ & 7)) << 3),                                      \
                &Atile[b_][r_ * 64 + sch * 8]);                                   \
    gload_lds16(W + (size_t)(n0 + r_) * ldk + koff + (T_) * 64 +                  \
                    ((sch ^ (r_ & 7)) << 3),                                      \
                &Btile[b_][r_ * 64 + sch * 8]);                                   \
  }

#define G256_MAINLOOP()                                                           \
  G256_STAGE1(0, 0, 0); G256_STAGE1(0, 0, 1);                                     \
  G256_STAGE1(0, 0, 2); G256_STAGE1(0, 0, 3);                                     \
  for (int T = 0; T < NT; ++T) {                                                  \
    const int b = T & 1;                                                          \
    const bool more = (T + 1 < NT);                                               \
    if (more) {                                                                   \
      G256_STAGE1(T + 1, b ^ 1, 0);                                               \
      asm volatile("s_waitcnt vmcnt(2)" ::: "memory");                            \
    } else {                                                                      \
      asm volatile("s_waitcnt vmcnt(0)" ::: "memory");                            \
    }                                                                             \
    __builtin_amdgcn_sched_barrier(0);                                            \
    __builtin_amdgcn_s_barrier();                                                 \
    _Pragma("unroll") for (int q = 0; q < 4; ++q) {                               \
      const int kk = q >> 1, mh = (q & 1) * 4;                                    \
      bf16x8 af[4], bfq[4];                                                       \
      _Pragma("unroll") for (int j = 0; j < 4; j++) {                             \
        const int ar = wr * 128 + (mh + j) * 16 + c;                              \
        const int br = wc * 64 + j * 16 + c;                                      \
        const int sl = ((kk * 4 + g) ^ (c & 7)) << 3;                             \
        af[j] = *(const bf16x8*)&Atile[b][ar * 64 + sl];                          \
        bfq[j] = *(const bf16x8*)&Btile[b][br * 64 + sl];                         \
      }                                                                           \
      if (q > 0 && more) G256_STAGE1(T + 1, b ^ 1, q);                            \
      __builtin_amdgcn_s_barrier();                                               \
      __builtin_amdgcn_s_setprio(1);                                              \
      _Pragma("unroll") for (int j = 0; j < 4; j++)                               \
        _Pragma("unroll") for (int n = 0; n < 4; n++)                             \
          acc[mh + j][n] = __builtin_amdgcn_mfma_f32_16x16x32_bf16(               \
              af[j], bfq[n], acc[mh + j][n], 0, 0, 0);                            \
      __builtin_amdgcn_s_setprio(0);                                              \
      __builtin_amdgcn_s_barrier();                                               \
    }                                                                             \
  }

// FFN1 (RELU=1, full K) / FFN2 (RELU=0, bf16 partials, split-K via blockIdx.z)
template <int RELU>
__global__ __launch_bounds__(512, 2) void gemm256(
    const unsigned short* __restrict__ A, const unsigned short* __restrict__ W,
    const float* __restrict__ bias, unsigned short* __restrict__ out,
    int M, int N, int KS) {
  __shared__ unsigned short Atile[2][256 * 64];
  __shared__ unsigned short Btile[2][256 * 64];
  const int t = threadIdx.x, lane = t & 63, wid = t >> 6;
  const int g = lane >> 4, c = lane & 15;
  const int wr = wid >> 2, wc = wid & 3;          // 2x4 wave grid
  const int m0 = blockIdx.y * 256, n0 = blockIdx.x * 256;
  const int srow = t >> 3, sch = t & 7;           // staging row / 16B-chunk
  const int NT = KS >> 6;
  const int ldk = KS * gridDim.z;
  const int koff = blockIdx.z * KS;
  (void)M;

  f32x4 zero = {0.f, 0.f, 0.f, 0.f};
  f32x4 acc[8][4];
#pragma unroll
  for (int i = 0; i < 8; i++)
#pragma unroll
    for (int j = 0; j < 4; j++) acc[i][j] = zero;

  G256_MAINLOOP();

  float bv[4];
#pragma unroll
  for (int ni = 0; ni < 4; ni++)
    bv[ni] = RELU ? bias[n0 + wc * 64 + ni * 16 + c] : 0.f;

  unsigned short* po = out + (RELU ? 0 : (size_t)blockIdx.z * M * N);

#pragma unroll
  for (int mi = 0; mi < 8; mi++) {
#pragma unroll
    for (int ni = 0; ni < 4; ni++) {
      const int mb = m0 + wr * 128 + mi * 16 + g * 4;
      const int n = n0 + wc * 64 + ni * 16 + c;
#pragma unroll
      for (int r = 0; r < 4; r++) {
        float v = acc[mi][ni][r] + bv[ni];
        if (RELU) v = fmaxf(v, 0.f);
        po[(size_t)(mb + r) * N + n] = f2bf(v);
      }
    }
  }
}

// QKV on the 256-tile structure: grid (4, 16, 3); blockIdx.z selects weight.
// Q written pre-scaled by 1/8; K plain; V written transposed Vt (B,H,dk,S).
__global__ __launch_bounds__(512, 2) void gemm256_qkv(
    const unsigned short* __restrict__ A, const unsigned short* __restrict__ Wbase,
    const float* __restrict__ bq, const float* __restrict__ bk,
    const float* __restrict__ bv_, unsigned short* __restrict__ qkout,
    unsigned short* __restrict__ vtout) {
  __shared__ unsigned short Atile[2][256 * 64];
  __shared__ unsigned short Btile[2][256 * 64];
  const int t = threadIdx.x, lane = t & 63, wid = t >> 6;
  const int g = lane >> 4, c = lane & 15;
  const int wr = wid >> 2, wc = wid & 3;
  const int m0 = blockIdx.y * 256, n0 = blockIdx.x * 256;
  const int srow = t >> 3, sch = t & 7;
  const int NT = 16;                              // K = 1024
  const int ldk = 1024, koff = 0;
  const int wsel = blockIdx.z;
  const unsigned short* W = Wbase + ((size_t)wsel << 20);
  const float* bias = (wsel == 0) ? bq : (wsel == 1) ? bk : bv_;

  f32x4 zero = {0.f, 0.f, 0.f, 0.f};
  f32x4 acc[8][4];
#pragma unroll
  for (int i = 0; i < 8; i++)
#pragma unroll
    for (int j = 0; j < 4; j++) acc[i][j] = zero;

  G256_MAINLOOP();

  float bvv[4];
#pragma unroll
  for (int ni = 0; ni < 4; ni++) bvv[ni] = bias[n0 + wc * 64 + ni * 16 + c];
  const float qsc = (wsel == 0) ? 0.125f : 1.f;

  if (wsel < 2) {
    unsigned short* outp = qkout + ((size_t)wsel << 22);  // q then k
#pragma unroll
    for (int mi = 0; mi < 8; mi++) {
#pragma unroll
      for (int ni = 0; ni < 4; ni++) {
        const int mb = m0 + wr * 128 + mi * 16 + g * 4;
        const int n = n0 + wc * 64 + ni * 16 + c;
#pragma unroll
        for (int r = 0; r < 4; r++)
          outp[(size_t)(mb + r) * 1024 + n] = f2bf((acc[mi][ni][r] + bvv[ni]) * qsc);
      }
    }
  } else {
    // V^T: vtout[(b*1024 + n)*2048 + s]; mb%4==0 so 4 r-values share b
#pragma unroll
    for (int mi = 0; mi < 8; mi++) {
#pragma unroll
      for (int ni = 0; ni < 4; ni++) {
        const int mb = m0 + wr * 128 + mi * 16 + g * 4;
        const int n = n0 + wc * 64 + ni * 16 + c;
        const int b = mb >> 11, s2 = mb & 2047;
        ushort4 o4;
        o4.x = f2bf(acc[mi][ni][0] + bvv[ni]);
        o4.y = f2bf(acc[mi][ni][1] + bvv[ni]);
        o4.z = f2bf(acc[mi][ni][2] + bvv[ni]);
        o4.w = f2bf(acc[mi][ni][3] + bvv[ni]);
        *(ushort4*)(vtout + ((size_t)(b * 1024 + n)) * 2048 + s2) = o4;
      }
    }
  }
}

// ---------------------------------------------------------------------------
// Flash attention, 8-wave blocks (proven round-15 version). grid = (B*H, S/128).
// ---------------------------------------------------------------------------
#define ATTN_STAGE64(base_, buf_)                                                   \
  {                                                                                 \
    const int r_ = t >> 3, ch_ = t & 7;                                             \
    gload_lds16(Kb + (size_t)((base_) + r_) * D_MODEL + ((ch_ ^ (r_ & 7)) << 3),    \
                &Klds[buf_][t * 8]);                                                \
    gload_lds16(Vb + (size_t)r_ * SEQ + (base_) + ((ch_ ^ (r_ & 7)) << 3),          \
                &Vlds[buf_][t * 8]);                                                \
  }

__global__ __launch_bounds__(512, 4) void attn_kernel(
    const unsigned short* __restrict__ Q, const unsigned short* __restrict__ Kmat,
    const unsigned short* __restrict__ Vt, const float* __restrict__ maskf,
    unsigned short* __restrict__ O) {
  __shared__ unsigned short Klds[2][64 * 64];
  __shared__ unsigned short Vlds[2][64 * 64];
  __shared__ float masklds[SEQ];
  const int t = threadIdx.x, lane = t & 63, wid = t >> 6;
  const int g = lane >> 4, c = lane & 15;
  const int bh = blockIdx.x, qt = blockIdx.y;   // bh on x => XCD = bh%8
  const int b = bh >> 4, h = bh & 15;
  const int q0 = qt * 128 + wid * 16;           // 8 waves x 16 q-rows

  const unsigned short* Qb = Q + (size_t)b * SEQ * D_MODEL + h * DKH;
  const unsigned short* Kb = Kmat + (size_t)b * SEQ * D_MODEL + h * DKH;
  const unsigned short* Vb = Vt + (size_t)bh * DKH * SEQ;
  const float* mbf = maskf + b * SEQ;

  bf16x8 qf[2];
#pragma unroll
  for (int kd = 0; kd < 2; kd++)
    qf[kd] = *(const bf16x8*)&Qb[(size_t)(q0 + c) * D_MODEL + kd * 32 + g * 8];

  f32x4 zero = {0.f, 0.f, 0.f, 0.f};
  f32x4 of[4];
#pragma unroll
  for (int j = 0; j < 4; j++) of[j] = zero;
  float mrun = -1e30f, lrun = 0.f;

  // stage mask addends (2048 floats = 8 KB, one gload/thread) + first K/V tile
  gload_lds16(mbf + t * 4, &masklds[t * 4]);
  ATTN_STAGE64(0, 0);

  for (int kv = 0; kv < 32; ++kv) {
    const int buf = kv & 1;
    const int base = kv * 64;
    __syncthreads();                        // drains this buf's gloads
    if (kv < 31) ATTN_STAGE64(base + 64, buf ^ 1);

    // --- QK^T: S^T[kv 64][q 16] per wave ---
    f32x4 sf[4];
    {
      bf16x8 kf0[4], kf1[4];
#pragma unroll
      for (int nb = 0; nb < 4; nb++) {
        const int row = nb * 16 + c;
        kf0[nb] = *(const bf16x8*)&Klds[buf][row * 64 + ((g ^ (c & 7)) << 3)];
        kf1[nb] = *(const bf16x8*)&Klds[buf][row * 64 + (((4 + g) ^ (c & 7)) << 3)];
      }
      __builtin_amdgcn_s_setprio(1);
#pragma unroll
      for (int nb = 0; nb < 4; nb++) {
        f32x4 s = zero;
        s = __builtin_amdgcn_mfma_f32_16x16x32_bf16(kf0[nb], qf[0], s, 0, 0, 0);
        s = __builtin_amdgcn_mfma_f32_16x16x32_bf16(kf1[nb], qf[1], s, 0, 0, 0);
        sf[nb] = s;
      }
      __builtin_amdgcn_s_setprio(0);
    }

    // additive mask (pre-converted 0/-1e9)
#pragma unroll
    for (int nb = 0; nb < 4; nb++) {
      float4 ma = *(const float4*)&masklds[base + nb * 16 + g * 4];
      sf[nb][0] += ma.x; sf[nb][1] += ma.y; sf[nb][2] += ma.z; sf[nb][3] += ma.w;
    }

    // online softmax with defer-max (THR=8)
    float pm = -1e30f;
#pragma unroll
    for (int nb = 0; nb < 4; nb++)
#pragma unroll
      for (int r = 0; r < 4; r++) pm = fmaxf(pm, sf[nb][r]);
    pm = fmaxf(pm, __shfl_xor(pm, 16, 64));
    pm = fmaxf(pm, __shfl_xor(pm, 32, 64));
    if (!__all(pm <= mrun + 8.f)) {
      float mnew = fmaxf(mrun, pm);
      float fsc = EXP2((mrun - mnew) * 1.44269504f);
      lrun *= fsc;
#pragma unroll
      for (int dkb = 0; dkb < 4; dkb++) of[dkb] *= fsc;
      mrun = mnew;
    }
    const float mb2 = mrun * 1.44269504f;
    float ps = 0.f;
#pragma unroll
    for (int nb = 0; nb < 4; nb++)
#pragma unroll
      for (int r = 0; r < 4; r++) {
        float p = EXP2(fmaf(sf[nb][r], 1.44269504f, -mb2));
        sf[nb][r] = p;
        ps += p;
      }
    lrun += ps;

    // --- PV: of[dkb] += V^T-frag x P^T-frag per 16-kv block nb.
#pragma unroll
    for (int nb = 0; nb < 4; nb++) {
      bf16x4 vv[4];
#pragma unroll
      for (int dkb = 0; dkb < 4; dkb++) {
        const int row = dkb * 16 + c;
        const int vbyte = row * 128 + ((((nb << 1) + (g >> 1)) ^ (c & 7)) << 4) +
                          ((g & 1) << 3);
        vv[dkb] = *(const bf16x4*)((const char*)Vlds[buf] + vbyte);
      }
      unsigned plo = packbf2(sf[nb][0], sf[nb][1]);
      unsigned phi = packbf2(sf[nb][2], sf[nb][3]);
      unsigned long long uu = (unsigned long long)plo |
                              ((unsigned long long)phi << 32);
      bf16x4 pf = __builtin_bit_cast(bf16x4, uu);
      __builtin_amdgcn_s_setprio(1);
#pragma unroll
      for (int dkb = 0; dkb < 4; dkb++)
        of[dkb] = MFMA16(vv[dkb], pf, of[dkb]);
      __builtin_amdgcn_s_setprio(0);
    }
  }

  float lt = lrun;
  lt += __shfl_xor(lt, 16, 64);
  lt += __shfl_xor(lt, 32, 64);
  float inv = 1.f / lt;
#pragma unroll
  for (int dkb = 0; dkb < 4; dkb++) {
    ushort4 o4;
    o4.x = f2bf(of[dkb][0] * inv);
    o4.y = f2bf(of[dkb][1] * inv);
    o4.z = f2bf(of[dkb][2] * inv);
    o4.w = f2bf(of[dkb][3] * inv);
    *(ushort4*)&O[(size_t)(b * SEQ + q0 + c) * D_MODEL + h * DKH + dkb * 16 +
                  g * 4] = o4;
  }
}

// ---------------------------------------------------------------------------
// Fused epilogues (bf16 split-K partials)
// proj_ln2: x2 = x + P0 + P1 + bo;  h2 = LN2(x2).  one block per row.
// ---------------------------------------------------------------------------
__global__ __launch_bounds__(256) void proj_ln2_kernel(
    const float* __restrict__ x, const unsigned short* __restrict__ P0,
    const unsigned short* __restrict__ P1, const float* __restrict__ bo,
    const float* __restrict__ alpha, const float* __restrict__ beta,
    float* __restrict__ x2, unsigned short* __restrict__ h2) {
  const int row = blockIdx.x;
  const int t = threadIdx.x;
  const size_t idx = (size_t)row * D_MODEL + t * 4;
  float4 xv = *(const float4*)(x + idx);
  ushort4 p0u = *(const ushort4*)(P0 + idx);
  ushort4 p1u = *(const ushort4*)(P1 + idx);
  float4 bo4 = *(const float4*)(bo + t * 4);
  float4 v;
  v.x = xv.x + bf2f(p0u.x) + bf2f(p1u.x) + bo4.x;
  v.y = xv.y + bf2f(p0u.y) + bf2f(p1u.y) + bo4.y;
  v.z = xv.z + bf2f(p0u.z) + bf2f(p1u.z) + bo4.z;
  v.w = xv.w + bf2f(p0u.w) + bf2f(p1u.w) + bo4.w;
  *(float4*)(x2 + idx) = v;

  float s = v.x + v.y + v.z + v.w;
#pragma unroll
  for (int o = 1; o < 64; o <<= 1) s += __shfl_xor(s, o, 64);
  __shared__ float red[8];
  if ((t & 63) == 0) red[t >> 6] = s;
  __syncthreads();
  float mean = (red[0] + red[1] + red[2] + red[3]) * (1.f / D_MODEL);
  float dx = v.x - mean, dy = v.y - mean, dz = v.z - mean, dw = v.w - mean;
  float sq = dx * dx + dy * dy + dz * dz + dw * dw;
#pragma unroll
  for (int o = 1; o < 64; o <<= 1) sq += __shfl_xor(sq, o, 64);
  if ((t & 63) == 0) red[4 + (t >> 6)] = sq;
  __syncthreads();
  float var = (red[4] + red[5] + red[6] + red[7]) * (1.f / (D_MODEL - 1));
  float inv = 1.f / (sqrtf(var) + 1e-6f);
  float4 a = *(const float4*)(alpha + t * 4);
  float4 be = *(const float4*)(beta + t * 4);
  ushort4 o4;
  o4.x = f2bf(a.x * dx * inv + be.x);
  o4.y = f2bf(a.y * dy * inv + be.y);
  o4.z = f2bf(a.z * dz * inv + be.z);
  o4.w = f2bf(a.w * dw * inv + be.w);
  *(ushort4*)(h2 + idx) = o4;
}

// ffn2_add: out = x2 + Q0+Q1+Q2+Q3 + b2  (final output, f32; bf16 partials x4)
__global__ __launch_bounds__(256) void ffn2_add_kernel(
    const float* __restrict__ x2, const unsigned short* __restrict__ Q0,
    const float* __restrict__ b2, float* __restrict__ out) {
  const int i4 = blockIdx.x * blockDim.x + threadIdx.x;  // 1M float4s
  const size_t idx = (size_t)i4 * 4;
  const size_t stride = (size_t)MROWS * D_MODEL;
  float4 a = *(const float4*)(x2 + idx);
  ushort4 q0u = *(const ushort4*)(Q0 + idx);
  ushort4 q1u = *(const ushort4*)(Q0 + stride + idx);
  ushort4 q2u = *(const ushort4*)(Q0 + 2 * stride + idx);
  ushort4 q3u = *(const ushort4*)(Q0 + 3 * stride + idx);
  float4 b = *(const float4*)(b2 + ((i4 & 255) * 4));
  float4 v;
  v.x = a.x + (bf2f(q0u.x) + bf2f(q1u.x)) + (bf2f(q2u.x) + bf2f(q3u.x)) + b.x;
  v.y = a.y + (bf2f(q0u.y) + bf2f(q1u.y)) + (bf2f(q2u.y) + bf2f(q3u.y)) + b.y;
  v.z = a.z + (bf2f(q0u.z) + bf2f(q1u.z)) + (bf2f(q2u.z) + bf2f(q3u.z)) + b.z;
  v.w = a.w + (bf2f(q0u.w) + bf2f(q1u.w)) + (bf2f(q2u.w) + bf2f(q3u.w)) + b.w;
  *(float4*)(out + idx) = v;
}

// ---------------------------------------------------------------------------
// Launch
// ---------------------------------------------------------------------------
extern "C" void kernel_launch(void* const* d_in, const int* in_sizes, int n_in,
                              void* d_out, int out_size, void* d_ws, size_t ws_size,
                              hipStream_t stream) {
  (void)in_sizes; (void)n_in; (void)out_size; (void)ws_size;
  const float* x    = (const float*)d_in[0];
  const int*   mask = (const int*)d_in[1];
  const float* wq   = (const float*)d_in[2];
  const float* bq   = (const float*)d_in[3];
  const float* wk   = (const float*)d_in[4];
  const float* bk   = (const float*)d_in[5];
  const float* wv   = (const float*)d_in[6];
  const float* bv   = (const float*)d_in[7];
  const float* wo   = (const float*)d_in[8];
  const float* bo   = (const float*)d_in[9];
  const float* w1   = (const float*)d_in[10];
  const float* b1   = (const float*)d_in[11];
  const float* w2   = (const float*)d_in[12];
  const float* b2   = (const float*)d_in[13];
  const float* ln1a = (const float*)d_in[14];
  const float* ln1b = (const float*)d_in[15];
  const float* ln2a = (const float*)d_in[16];
  const float* ln2b = (const float*)d_in[17];

  char* ws = (char*)d_ws;
  unsigned short* w_bf  = (unsigned short*)ws;            // 24 MB bf16 weights
  unsigned short* wq_bf = w_bf;
  unsigned short* wo_bf = w_bf + (3u << 20);
  unsigned short* w1_bf = w_bf + (4u << 20);
  unsigned short* w2_bf = w_bf + (8u << 20);
  unsigned short* h1    = (unsigned short*)(ws + (24u << 20));
  unsigned short* qbuf  = (unsigned short*)(ws + (32u << 20));
  unsigned short* kbuf  = (unsigned short*)(ws + (40u << 20));
  unsigned short* vtbuf = (unsigned short*)(ws + (48u << 20));
  unsigned short* attnb = (unsigned short*)(ws + (56u << 20));
  float*          x2    = (float*)(ws + (64u << 20));     // 16 MB
  unsigned short* h2    = (unsigned short*)(ws + (80u << 20));
  unsigned short* ffn1  = (unsigned short*)(ws + (88u << 20));  // 32 MB -> 120
  unsigned short* pp    = (unsigned short*)(ws + (88u << 20)); // proj partials
                                                          // (2x8MB, dead before
                                                          // ffn1 use)
  unsigned short* qq    = (unsigned short*)(ws + (24u << 20)); // ffn2 partials
                                                          // (4x8MB = 24..56MB;
                                                          // h1..attnb dead)
  float*          maskf = (float*)(ws + (120u << 20));    // 16 KB

  prep_kernel<<<MROWS + 1024, 256, 0, stream>>>(
      x, ln1a, ln1b, h1, wq, wk, wv, wo, w1, w2, mask, w_bf, maskf);
  gemm256_qkv<<<dim3(4, 16, 3), 512, 0, stream>>>(
      h1, wq_bf, bq, bk, bv, qbuf, vtbuf);
  attn_kernel<<<dim3(32, 16), 512, 0, stream>>>(qbuf, kbuf, vtbuf, maskf, attnb);
  gemm_bt<MODE_PARTIAL><<<dim3(8, 32, 2), 256, 0, stream>>>(
      attnb, wo_bf, nullptr, (void*)pp, MROWS, D_MODEL, 512);
  proj_ln2_kernel<<<MROWS, 256, 0, stream>>>(
      x, pp, pp + (size_t)MROWS * D_MODEL, bo, ln2a, ln2b, x2, h2);
  gemm256<1><<<dim3(16, 16), 512, 0, stream>>>(
      h2, w1_bf, b1, ffn1, MROWS, DFF, D_MODEL);
  gemm256<0><<<dim3(4, 16, 4), 512, 0, stream>>>(
      ffn1, w2_bf, nullptr, qq, MROWS, D_MODEL, 1024);
  ffn2_add_kernel<<<4096, 256, 0, stream>>>(x2, qq, b2, (float*)d_out);
}

// Round 21
// 240.601 us; speedup vs baseline: 1.0194x; 1.0065x over previous
//
#include <hip/hip_runtime.h>
#include <cstdint>
#include <cstddef>

// ---------------------------------------------------------------------------
// Types / helpers
// ---------------------------------------------------------------------------
typedef short bf16x8 __attribute__((ext_vector_type(8)));
typedef short bf16x4 __attribute__((ext_vector_type(4)));
typedef float f32x4 __attribute__((ext_vector_type(4)));

#define D_MODEL 1024
#define SEQ     2048
#define NBATCH  2
#define NH      16
#define DKH     64
#define DFF     4096
#define MROWS   (NBATCH * SEQ)   // 4096

#if defined(__HIP_DEVICE_COMPILE__)
#if __has_builtin(__builtin_amdgcn_mfma_f32_16x16x16bf16_1k)
#define MFMA16(a, b, c) __builtin_amdgcn_mfma_f32_16x16x16bf16_1k(a, b, c, 0, 0, 0)
#else
#define MFMA16(a, b, c) __builtin_amdgcn_mfma_f32_16x16x16_bf16(a, b, c, 0, 0, 0)
#endif
#if __has_builtin(__builtin_amdgcn_exp2f)
#define EXP2(x) __builtin_amdgcn_exp2f(x)
#else
#define EXP2(x) exp2f(x)
#endif
#else
__device__ __host__ static inline f32x4 MFMA16(bf16x4, bf16x4, f32x4 c) {
  return c;
}
#define EXP2(x) exp2f(x)
#endif

__device__ __forceinline__ unsigned short f2bf(float f) {
  unsigned u = __builtin_bit_cast(unsigned, f);
  u += 0x7fffu + ((u >> 16) & 1u);          // round-to-nearest-even
  return (unsigned short)(u >> 16);
}
__device__ __forceinline__ float bf2f(unsigned short u) {
  return __builtin_bit_cast(float, (unsigned)u << 16);
}
__device__ __forceinline__ unsigned packbf2(float lo, float hi) {
  unsigned r;
  asm("v_cvt_pk_bf16_f32 %0, %1, %2" : "=v"(r) : "v"(lo), "v"(hi));
  return r;
}
__device__ __forceinline__ void gload_lds16(const void* g, void* l) {
  __builtin_amdgcn_global_load_lds(
      (const __attribute__((address_space(1))) unsigned*)g,
      (__attribute__((address_space(3))) unsigned*)l, 16, 0, 0);
}

// ---------------------------------------------------------------------------
// prep: blocks <4096 do LN1 (one row each, torch semantics); blocks >=4096 do
// weight cast f32->bf16 (dst: [wq 1M][wk 1M][wv 1M][wo 1M][w1 4M][w2 4M]) and
// mask -> float addend (0/-1e9).
// ---------------------------------------------------------------------------
__global__ __launch_bounds__(256) void prep_kernel(
    const float* __restrict__ x, const float* __restrict__ alpha,
    const float* __restrict__ beta, unsigned short* __restrict__ h1,
    const float* __restrict__ wq, const float* __restrict__ wk,
    const float* __restrict__ wv, const float* __restrict__ wo,
    const float* __restrict__ w1, const float* __restrict__ w2,
    const int* __restrict__ mask, unsigned short* __restrict__ dst,
    float* __restrict__ maskf) {
  const int t = threadIdx.x;
  if (blockIdx.x < MROWS) {
    // ---- LayerNorm row ----
    const int row = blockIdx.x;
    float4 v = *(const float4*)(x + (size_t)row * D_MODEL + t * 4);
    float s = v.x + v.y + v.z + v.w;
#pragma unroll
    for (int o = 1; o < 64; o <<= 1) s += __shfl_xor(s, o, 64);
    __shared__ float red[8];
    if ((t & 63) == 0) red[t >> 6] = s;
    __syncthreads();
    float mean = (red[0] + red[1] + red[2] + red[3]) * (1.f / D_MODEL);
    float dx = v.x - mean, dy = v.y - mean, dz = v.z - mean, dw = v.w - mean;
    float sq = dx * dx + dy * dy + dz * dz + dw * dw;
#pragma unroll
    for (int o = 1; o < 64; o <<= 1) sq += __shfl_xor(sq, o, 64);
    if ((t & 63) == 0) red[4 + (t >> 6)] = sq;
    __syncthreads();
    float var = (red[4] + red[5] + red[6] + red[7]) * (1.f / (D_MODEL - 1));
    float inv = 1.f / (sqrtf(var) + 1e-6f);
    float4 a = *(const float4*)(alpha + t * 4);
    float4 be = *(const float4*)(beta + t * 4);
    ushort4 o4;
    o4.x = f2bf(a.x * dx * inv + be.x);
    o4.y = f2bf(a.y * dy * inv + be.y);
    o4.z = f2bf(a.z * dz * inv + be.z);
    o4.w = f2bf(a.w * dw * inv + be.w);
    *(ushort4*)(h1 + (size_t)row * D_MODEL + t * 4) = o4;
  } else {
    // ---- weight cast + mask convert ----
    const int TOT4 = (12 << 20) >> 2;
    const int gid = (blockIdx.x - MROWS) * 256 + t;
    for (int i4 = gid; i4 < TOT4; i4 += 1024 * 256) {
      int i = i4 << 2;
      const float* src;
      int off;
      if (i < (4 << 20)) {
        src = (i < (2 << 20)) ? ((i < (1 << 20)) ? wq : wk)
                              : ((i < (3 << 20)) ? wv : wo);
        off = i & ((1 << 20) - 1);
      } else if (i < (8 << 20)) { src = w1; off = i - (4 << 20); }
      else                      { src = w2; off = i - (8 << 20); }
      float4 v = *(const float4*)(src + off);
      ushort4 o;
      o.x = f2bf(v.x); o.y = f2bf(v.y); o.z = f2bf(v.z); o.w = f2bf(v.w);
      *(ushort4*)(dst + i) = o;
    }
    if (gid < (NBATCH * SEQ / 4)) {
      int4 m = ((const int4*)mask)[gid];
      float4 f;
      f.x = (m.x == 0) ? -1e9f : 0.f;
      f.y = (m.y == 0) ? -1e9f : 0.f;
      f.z = (m.z == 0) ? -1e9f : 0.f;
      f.w = (m.w == 0) ? -1e9f : 0.f;
      ((float4*)maskf)[gid] = f;
    }
  }
}

// ---------------------------------------------------------------------------
// GEMM core macros (128x128 tile, BK=32, 4 waves 2x2, double-buffered LDS)
// ---------------------------------------------------------------------------
#define GEMM_STAGE(A_, W_, LD_, koff_, kt_, buf_)                                  \
  {                                                                                \
    int ke_ = (koff_) + (kt_) * 32;                                                \
    gload_lds16(A_ + (size_t)(m0 + srow) * (LD_) + ke_ + sce, &lds[(buf_)][0][t * 8]);        \
    gload_lds16(A_ + (size_t)(m0 + 64 + srow) * (LD_) + ke_ + sce, &lds[(buf_)][0][2048 + t * 8]); \
    gload_lds16(W_ + (size_t)(n0 + srow) * (LD_) + ke_ + sce, &lds[(buf_)][1][t * 8]);        \
    gload_lds16(W_ + (size_t)(n0 + 64 + srow) * (LD_) + ke_ + sce, &lds[(buf_)][1][2048 + t * 8]); \
  }

#define GEMM_MAINLOOP(A_, W_, LD_, K_, koff_)                                      \
  GEMM_STAGE(A_, W_, LD_, koff_, 0, 0);                                            \
  for (int kt = 0; kt < ((K_) >> 5); ++kt) {                                       \
    __syncthreads();                                                               \
    if (kt + 1 < ((K_) >> 5)) GEMM_STAGE(A_, W_, LD_, koff_, kt + 1, (kt + 1) & 1); \
    const unsigned short* la = lds[kt & 1][0];                                     \
    const unsigned short* lb = lds[kt & 1][1];                                     \
    bf16x8 af[4], bfr[4];                                                          \
    _Pragma("unroll") for (int i = 0; i < 4; i++) {                                \
      af[i]  = *(const bf16x8*)&la[(wm + i * 16 + c) * 32 + g * 8];                \
      bfr[i] = *(const bf16x8*)&lb[(wn + i * 16 + c) * 32 + g * 8];                \
    }                                                                              \
    _Pragma("unroll") for (int mi = 0; mi < 4; mi++)                               \
      _Pragma("unroll") for (int ni = 0; ni < 4; ni++)                             \
        acc[mi][ni] = __builtin_amdgcn_mfma_f32_16x16x32_bf16(af[mi], bfr[ni],     \
                                                              acc[mi][ni], 0, 0, 0); \
  }

enum { MODE_BF16 = 0, MODE_RELU = 2, MODE_PARTIAL = 4 };

template <int MODE>
__global__ __launch_bounds__(256) void gemm_bt(
    const unsigned short* __restrict__ A, const unsigned short* __restrict__ W,
    const float* __restrict__ bias, void* __restrict__ outp, int M, int N, int K) {
  __shared__ unsigned short lds[2][2][128 * 32];
  const int t = threadIdx.x;
  const int lane = t & 63, wid = t >> 6;
  const int g = lane >> 4, c = lane & 15;
  const int m0 = blockIdx.y * 128, n0 = blockIdx.x * 128;
  const int wm = (wid >> 1) * 64, wn = (wid & 1) * 64;
  const int srow = t >> 2, sce = (t & 3) * 8;
  const int ldk = K * gridDim.z;
  const int koff = blockIdx.z * K;

  f32x4 zero = {0.f, 0.f, 0.f, 0.f};
  f32x4 acc[4][4];
#pragma unroll
  for (int i = 0; i < 4; i++)
#pragma unroll
    for (int j = 0; j < 4; j++) acc[i][j] = zero;

  GEMM_MAINLOOP(A, W, ldk, K, koff);

  float bv[4];
#pragma unroll
  for (int ni = 0; ni < 4; ni++)
    bv[ni] = (MODE == MODE_PARTIAL) ? 0.f : bias[n0 + wn + ni * 16 + c];

  unsigned short* po = (unsigned short*)outp +
                       ((MODE == MODE_PARTIAL) ? (size_t)blockIdx.z * M * N : 0);

#pragma unroll
  for (int mi = 0; mi < 4; mi++) {
#pragma unroll
    for (int ni = 0; ni < 4; ni++) {
      const int mb = m0 + wm + mi * 16 + g * 4;
      const int n = n0 + wn + ni * 16 + c;
#pragma unroll
      for (int r = 0; r < 4; r++) {
        const int m = mb + r;
        float v = acc[mi][ni][r] + bv[ni];
        if (MODE == MODE_RELU) v = fmaxf(v, 0.f);
        po[(size_t)m * N + n] = f2bf(v);   // bf16 partials / outputs
      }
    }
  }
}

// ---------------------------------------------------------------------------
// 256x256-tile 4-phase GEMM main-loop macro, fine-grained interleave
// (m201-style). Per K-tile T: {issue 2 gloads of T+1 -> vmcnt(2) -> barrier ->
// 4 x phase[8 ds_read_b128 ; 2 more gloads ; barrier ; setprio+16 MFMA ;
// barrier]}.  Requires locals: A, W, ldk, koff, m0, n0, srow, sch, wr, wc,
// g, c, Atile, Btile, acc, NT.
// ---------------------------------------------------------------------------
#define G256_STAGE1(T_, b_, i_)                                                    \
  {                                                                               \
    const int r_ = srow + (i_) * 64;                                              \
    gload_lds16(A + (size_t)(m0 + r_) * ldk + koff + (T_) * 64 +                  \
                    ((sch ^ (r_ & 7)) << 3),                                      \
                &Atile[b_][r_ * 64 + sch * 8]);                                   \
    gload_lds16(W + (size_t)(n0 + r_) * ldk + koff + (T_) * 64 +                  \
                    ((sch ^ (r_ & 7)) << 3),                                      \
                &Btile[b_][r_ * 64 + sch * 8]);                                   \
  }

#define G256_MAINLOOP()                                                           \
  G256_STAGE1(0, 0, 0); G256_STAGE1(0, 0, 1);                                     \
  G256_STAGE1(0, 0, 2); G256_STAGE1(0, 0, 3);                                     \
  for (int T = 0; T < NT; ++T) {                                                  \
    const int b = T & 1;                                                          \
    const bool more = (T + 1 < NT);                                               \
    if (more) {                                                                   \
      G256_STAGE1(T + 1, b ^ 1, 0);                                               \
      asm volatile("s_waitcnt vmcnt(2)" ::: "memory");                            \
    } else {                                                                      \
      asm volatile("s_waitcnt vmcnt(0)" ::: "memory");                            \
    }                                                                             \
    __builtin_amdgcn_sched_barrier(0);                                            \
    __builtin_amdgcn_s_barrier();                                                 \
    _Pragma("unroll") for (int q = 0; q < 4; ++q) {                               \
      const int kk = q >> 1, mh = (q & 1) * 4;                                    \
      bf16x8 af[4], bfq[4];                                                       \
      _Pragma("unroll") for (int j = 0; j < 4; j++) {                             \
        const int ar = wr * 128 + (mh + j) * 16 + c;                              \
        const int br = wc * 64 + j * 16 + c;                                      \
        const int sl = ((kk * 4 + g) ^ (c & 7)) << 3;                             \
        af[j] = *(const bf16x8*)&Atile[b][ar * 64 + sl];                          \
        bfq[j] = *(const bf16x8*)&Btile[b][br * 64 + sl];                         \
      }                                                                           \
      if (q > 0 && more) G256_STAGE1(T + 1, b ^ 1, q);                            \
      __builtin_amdgcn_s_barrier();                                               \
      __builtin_amdgcn_s_setprio(1);                                              \
      _Pragma("unroll") for (int j = 0; j < 4; j++)                               \
        _Pragma("unroll") for (int n = 0; n < 4; n++)                             \
          acc[mh + j][n] = __builtin_amdgcn_mfma_f32_16x16x32_bf16(               \
              af[j], bfq[n], acc[mh + j][n], 0, 0, 0);                            \
      __builtin_amdgcn_s_setprio(0);                                              \
      __builtin_amdgcn_s_barrier();                                               \
    }                                                                             \
  }

// FFN1 (RELU=1, full K) / FFN2 (RELU=0, bf16 partials, split-K via blockIdx.z)
template <int RELU>
__global__ __launch_bounds__(512, 2) void gemm256(
    const unsigned short* __restrict__ A, const unsigned short* __restrict__ W,
    const float* __restrict__ bias, unsigned short* __restrict__ out,
    int M, int N, int KS) {
  __shared__ unsigned short Atile[2][256 * 64];
  __shared__ unsigned short Btile[2][256 * 64];
  const int t = threadIdx.x, lane = t & 63, wid = t >> 6;
  const int g = lane >> 4, c = lane & 15;
  const int wr = wid >> 2, wc = wid & 3;          // 2x4 wave grid
  const int m0 = blockIdx.y * 256, n0 = blockIdx.x * 256;
  const int srow = t >> 3, sch = t & 7;           // staging row / 16B-chunk
  const int NT = KS >> 6;
  const int ldk = KS * gridDim.z;
  const int koff = blockIdx.z * KS;
  (void)M;

  f32x4 zero = {0.f, 0.f, 0.f, 0.f};
  f32x4 acc[8][4];
#pragma unroll
  for (int i = 0; i < 8; i++)
#pragma unroll
    for (int j = 0; j < 4; j++) acc[i][j] = zero;

  G256_MAINLOOP();

  float bv[4];
#pragma unroll
  for (int ni = 0; ni < 4; ni++)
    bv[ni] = RELU ? bias[n0 + wc * 64 + ni * 16 + c] : 0.f;

  unsigned short* po = out + (RELU ? 0 : (size_t)blockIdx.z * M * N);

#pragma unroll
  for (int mi = 0; mi < 8; mi++) {
#pragma unroll
    for (int ni = 0; ni < 4; ni++) {
      const int mb = m0 + wr * 128 + mi * 16 + g * 4;
      const int n = n0 + wc * 64 + ni * 16 + c;
#pragma unroll
      for (int r = 0; r < 4; r++) {
        float v = acc[mi][ni][r] + bv[ni];
        if (RELU) v = fmaxf(v, 0.f);
        po[(size_t)(mb + r) * N + n] = f2bf(v);
      }
    }
  }
}

// QKV on the 256-tile structure: grid (4, 16, 3); blockIdx.z selects weight.
// Q written pre-scaled by 1/8; K plain; V written transposed Vt (B,H,dk,S).
__global__ __launch_bounds__(512, 2) void gemm256_qkv(
    const unsigned short* __restrict__ A, const unsigned short* __restrict__ Wbase,
    const float* __restrict__ bq, const float* __restrict__ bk,
    const float* __restrict__ bv_, unsigned short* __restrict__ qkout,
    unsigned short* __restrict__ vtout) {
  __shared__ unsigned short Atile[2][256 * 64];
  __shared__ unsigned short Btile[2][256 * 64];
  const int t = threadIdx.x, lane = t & 63, wid = t >> 6;
  const int g = lane >> 4, c = lane & 15;
  const int wr = wid >> 2, wc = wid & 3;
  const int m0 = blockIdx.y * 256, n0 = blockIdx.x * 256;
  const int srow = t >> 3, sch = t & 7;
  const int NT = 16;                              // K = 1024
  const int ldk = 1024, koff = 0;
  const int wsel = blockIdx.z;
  const unsigned short* W = Wbase + ((size_t)wsel << 20);
  const float* bias = (wsel == 0) ? bq : (wsel == 1) ? bk : bv_;

  f32x4 zero = {0.f, 0.f, 0.f, 0.f};
  f32x4 acc[8][4];
#pragma unroll
  for (int i = 0; i < 8; i++)
#pragma unroll
    for (int j = 0; j < 4; j++) acc[i][j] = zero;

  G256_MAINLOOP();

  float bvv[4];
#pragma unroll
  for (int ni = 0; ni < 4; ni++) bvv[ni] = bias[n0 + wc * 64 + ni * 16 + c];
  const float qsc = (wsel == 0) ? 0.125f : 1.f;

  if (wsel < 2) {
    unsigned short* outp = qkout + ((size_t)wsel << 22);  // q then k
#pragma unroll
    for (int mi = 0; mi < 8; mi++) {
#pragma unroll
      for (int ni = 0; ni < 4; ni++) {
        const int mb = m0 + wr * 128 + mi * 16 + g * 4;
        const int n = n0 + wc * 64 + ni * 16 + c;
#pragma unroll
        for (int r = 0; r < 4; r++)
          outp[(size_t)(mb + r) * 1024 + n] = f2bf((acc[mi][ni][r] + bvv[ni]) * qsc);
      }
    }
  } else {
    // V^T: vtout[(b*1024 + n)*2048 + s]; mb%4==0 so 4 r-values share b
#pragma unroll
    for (int mi = 0; mi < 8; mi++) {
#pragma unroll
      for (int ni = 0; ni < 4; ni++) {
        const int mb = m0 + wr * 128 + mi * 16 + g * 4;
        const int n = n0 + wc * 64 + ni * 16 + c;
        const int b = mb >> 11, s2 = mb & 2047;
        ushort4 o4;
        o4.x = f2bf(acc[mi][ni][0] + bvv[ni]);
        o4.y = f2bf(acc[mi][ni][1] + bvv[ni]);
        o4.z = f2bf(acc[mi][ni][2] + bvv[ni]);
        o4.w = f2bf(acc[mi][ni][3] + bvv[ni]);
        *(ushort4*)(vtout + ((size_t)(b * 1024 + n)) * 2048 + s2) = o4;
      }
    }
  }
}

// ---------------------------------------------------------------------------
// Flash attention, 8-wave blocks, KV tile = 128 (16 iterations -- per-tile
// fixed overhead halved vs KVBLK=64). grid = (B*H, S/128): XCD = bh%8.
// K tile [128 kv][64 d] (16 KB), V^T tile [64 dk][128 kv] (16 KB), both
// double-buffered + 8 KB mask = 72 KB LDS -> 2 blocks/CU (16 waves/CU, same
// as KVBLK=64 build). K swizzle unchanged (chunk ^ (row&7)); V has 16 chunks:
// swz keeps bit 3, XORs low 3 bits with row&7 (same involution staged and
// read). K fragments loaded per-nb inside the QK loop to cap VGPR.
// ---------------------------------------------------------------------------
#define VSWZ(ch_, r_) (((ch_) & 8) | (((ch_) ^ ((r_) & 7)) & 7))

#define ATTN_STAGE128(base_, buf_)                                                  \
  {                                                                                 \
    const int kr0_ = t >> 3, kr1_ = 64 + (t >> 3), kch_ = t & 7;                    \
    gload_lds16(Kb + (size_t)((base_) + kr0_) * D_MODEL +                           \
                    ((kch_ ^ (kr0_ & 7)) << 3), &Klds[buf_][t * 8]);                \
    gload_lds16(Kb + (size_t)((base_) + kr1_) * D_MODEL +                           \
                    ((kch_ ^ (kr1_ & 7)) << 3), &Klds[buf_][4096 + t * 8]);         \
    const int vr0_ = t >> 4, vr1_ = 32 + (t >> 4), vch_ = t & 15;                   \
    gload_lds16(Vb + (size_t)vr0_ * SEQ + (base_) + (VSWZ(vch_, vr0_) << 3),        \
                &Vlds[buf_][t * 8]);                                                \
    gload_lds16(Vb + (size_t)vr1_ * SEQ + (base_) + (VSWZ(vch_, vr1_) << 3),        \
                &Vlds[buf_][4096 + t * 8]);                                         \
  }

__global__ __launch_bounds__(512, 4) void attn_kernel(
    const unsigned short* __restrict__ Q, const unsigned short* __restrict__ Kmat,
    const unsigned short* __restrict__ Vt, const float* __restrict__ maskf,
    unsigned short* __restrict__ O) {
  __shared__ unsigned short Klds[2][128 * 64];
  __shared__ unsigned short Vlds[2][64 * 128];
  __shared__ float masklds[SEQ];
  const int t = threadIdx.x, lane = t & 63, wid = t >> 6;
  const int g = lane >> 4, c = lane & 15;
  const int bh = blockIdx.x, qt = blockIdx.y;   // bh on x => XCD = bh%8
  const int b = bh >> 4, h = bh & 15;
  const int q0 = qt * 128 + wid * 16;           // 8 waves x 16 q-rows

  const unsigned short* Qb = Q + (size_t)b * SEQ * D_MODEL + h * DKH;
  const unsigned short* Kb = Kmat + (size_t)b * SEQ * D_MODEL + h * DKH;
  const unsigned short* Vb = Vt + (size_t)bh * DKH * SEQ;
  const float* mbf = maskf + b * SEQ;

  bf16x8 qf[2];
#pragma unroll
  for (int kd = 0; kd < 2; kd++)
    qf[kd] = *(const bf16x8*)&Qb[(size_t)(q0 + c) * D_MODEL + kd * 32 + g * 8];

  f32x4 zero = {0.f, 0.f, 0.f, 0.f};
  f32x4 of[4];
#pragma unroll
  for (int j = 0; j < 4; j++) of[j] = zero;
  float mrun = -1e30f, lrun = 0.f;

  // stage mask addends (2048 floats = 8 KB, one gload/thread) + first K/V tile
  gload_lds16(mbf + t * 4, &masklds[t * 4]);
  ATTN_STAGE128(0, 0);

  for (int kv = 0; kv < 16; ++kv) {
    const int buf = kv & 1;
    const int base = kv * 128;
    __syncthreads();                        // drains this buf's gloads
    if (kv < 15) ATTN_STAGE128(base + 128, buf ^ 1);

    // --- QK^T: S^T[kv 128][q 16] per wave; K fragments loaded per-nb ---
    f32x4 sf[8];
    __builtin_amdgcn_s_setprio(1);
#pragma unroll
    for (int nb = 0; nb < 8; nb++) {
      const int row = nb * 16 + c;
      bf16x8 kf0 = *(const bf16x8*)&Klds[buf][row * 64 + ((g ^ (c & 7)) << 3)];
      bf16x8 kf1 = *(const bf16x8*)&Klds[buf][row * 64 + (((4 + g) ^ (c & 7)) << 3)];
      f32x4 s = zero;
      s = __builtin_amdgcn_mfma_f32_16x16x32_bf16(kf0, qf[0], s, 0, 0, 0);
      s = __builtin_amdgcn_mfma_f32_16x16x32_bf16(kf1, qf[1], s, 0, 0, 0);
      sf[nb] = s;
    }
    __builtin_amdgcn_s_setprio(0);

    // additive mask (pre-converted 0/-1e9)
#pragma unroll
    for (int nb = 0; nb < 8; nb++) {
      float4 ma = *(const float4*)&masklds[base + nb * 16 + g * 4];
      sf[nb][0] += ma.x; sf[nb][1] += ma.y; sf[nb][2] += ma.z; sf[nb][3] += ma.w;
    }

    // online softmax with defer-max (THR=8)
    float pm = -1e30f;
#pragma unroll
    for (int nb = 0; nb < 8; nb++)
#pragma unroll
      for (int r = 0; r < 4; r++) pm = fmaxf(pm, sf[nb][r]);
    pm = fmaxf(pm, __shfl_xor(pm, 16, 64));
    pm = fmaxf(pm, __shfl_xor(pm, 32, 64));
    if (!__all(pm <= mrun + 8.f)) {
      float mnew = fmaxf(mrun, pm);
      float fsc = EXP2((mrun - mnew) * 1.44269504f);
      lrun *= fsc;
#pragma unroll
      for (int dkb = 0; dkb < 4; dkb++) of[dkb] *= fsc;
      mrun = mnew;
    }
    const float mb2 = mrun * 1.44269504f;
    float ps = 0.f;
#pragma unroll
    for (int nb = 0; nb < 8; nb++)
#pragma unroll
      for (int r = 0; r < 4; r++) {
        float p = EXP2(fmaf(sf[nb][r], 1.44269504f, -mb2));
        sf[nb][r] = p;
        ps += p;
      }
    lrun += ps;

    // --- PV: of[dkb] += V^T-frag x P^T-frag per 16-kv block nb (0..7).
    // logical chunk q = 2nb + (g>>1) in [0,16); stored chunk = VSWZ(q, c&7).
#pragma unroll
    for (int nb = 0; nb < 8; nb++) {
      const int qc = 2 * nb + (g >> 1);
      bf16x4 vv[4];
#pragma unroll
      for (int dkb = 0; dkb < 4; dkb++) {
        const int row = dkb * 16 + c;
        const int vbyte = row * 256 + (VSWZ(qc, c) << 4) + ((g & 1) << 3);
        vv[dkb] = *(const bf16x4*)((const char*)Vlds[buf] + vbyte);
      }
      unsigned plo = packbf2(sf[nb][0], sf[nb][1]);
      unsigned phi = packbf2(sf[nb][2], sf[nb][3]);
      unsigned long long uu = (unsigned long long)plo |
                              ((unsigned long long)phi << 32);
      bf16x4 pf = __builtin_bit_cast(bf16x4, uu);
      __builtin_amdgcn_s_setprio(1);
#pragma unroll
      for (int dkb = 0; dkb < 4; dkb++)
        of[dkb] = MFMA16(vv[dkb], pf, of[dkb]);
      __builtin_amdgcn_s_setprio(0);
    }
  }

  float lt = lrun;
  lt += __shfl_xor(lt, 16, 64);
  lt += __shfl_xor(lt, 32, 64);
  float inv = 1.f / lt;
#pragma unroll
  for (int dkb = 0; dkb < 4; dkb++) {
    ushort4 o4;
    o4.x = f2bf(of[dkb][0] * inv);
    o4.y = f2bf(of[dkb][1] * inv);
    o4.z = f2bf(of[dkb][2] * inv);
    o4.w = f2bf(of[dkb][3] * inv);
    *(ushort4*)&O[(size_t)(b * SEQ + q0 + c) * D_MODEL + h * DKH + dkb * 16 +
                  g * 4] = o4;
  }
}

// ---------------------------------------------------------------------------
// Fused epilogues (bf16 split-K partials)
// proj_ln2: x2 = x + P0 + P1 + bo;  h2 = LN2(x2).  one block per row.
// ---------------------------------------------------------------------------
__global__ __launch_bounds__(256) void proj_ln2_kernel(
    const float* __restrict__ x, const unsigned short* __restrict__ P0,
    const unsigned short* __restrict__ P1, const float* __restrict__ bo,
    const float* __restrict__ alpha, const float* __restrict__ beta,
    float* __restrict__ x2, unsigned short* __restrict__ h2) {
  const int row = blockIdx.x;
  const int t = threadIdx.x;
  const size_t idx = (size_t)row * D_MODEL + t * 4;
  float4 xv = *(const float4*)(x + idx);
  ushort4 p0u = *(const ushort4*)(P0 + idx);
  ushort4 p1u = *(const ushort4*)(P1 + idx);
  float4 bo4 = *(const float4*)(bo + t * 4);
  float4 v;
  v.x = xv.x + bf2f(p0u.x) + bf2f(p1u.x) + bo4.x;
  v.y = xv.y + bf2f(p0u.y) + bf2f(p1u.y) + bo4.y;
  v.z = xv.z + bf2f(p0u.z) + bf2f(p1u.z) + bo4.z;
  v.w = xv.w + bf2f(p0u.w) + bf2f(p1u.w) + bo4.w;
  *(float4*)(x2 + idx) = v;

  float s = v.x + v.y + v.z + v.w;
#pragma unroll
  for (int o = 1; o < 64; o <<= 1) s += __shfl_xor(s, o, 64);
  __shared__ float red[8];
  if ((t & 63) == 0) red[t >> 6] = s;
  __syncthreads();
  float mean = (red[0] + red[1] + red[2] + red[3]) * (1.f / D_MODEL);
  float dx = v.x - mean, dy = v.y - mean, dz = v.z - mean, dw = v.w - mean;
  float sq = dx * dx + dy * dy + dz * dz + dw * dw;
#pragma unroll
  for (int o = 1; o < 64; o <<= 1) sq += __shfl_xor(sq, o, 64);
  if ((t & 63) == 0) red[4 + (t >> 6)] = sq;
  __syncthreads();
  float var = (red[4] + red[5] + red[6] + red[7]) * (1.f / (D_MODEL - 1));
  float inv = 1.f / (sqrtf(var) + 1e-6f);
  float4 a = *(const float4*)(alpha + t * 4);
  float4 be = *(const float4*)(beta + t * 4);
  ushort4 o4;
  o4.x = f2bf(a.x * dx * inv + be.x);
  o4.y = f2bf(a.y * dy * inv + be.y);
  o4.z = f2bf(a.z * dz * inv + be.z);
  o4.w = f2bf(a.w * dw * inv + be.w);
  *(ushort4*)(h2 + idx) = o4;
}

// ffn2_add: out = x2 + Q0+Q1+Q2+Q3 + b2  (final output, f32; bf16 partials x4)
__global__ __launch_bounds__(256) void ffn2_add_kernel(
    const float* __restrict__ x2, const unsigned short* __restrict__ Q0,
    const float* __restrict__ b2, float* __restrict__ out) {
  const int i4 = blockIdx.x * blockDim.x + threadIdx.x;  // 1M float4s
  const size_t idx = (size_t)i4 * 4;
  const size_t stride = (size_t)MROWS * D_MODEL;
  float4 a = *(const float4*)(x2 + idx);
  ushort4 q0u = *(const ushort4*)(Q0 + idx);
  ushort4 q1u = *(const ushort4*)(Q0 + stride + idx);
  ushort4 q2u = *(const ushort4*)(Q0 + 2 * stride + idx);
  ushort4 q3u = *(const ushort4*)(Q0 + 3 * stride + idx);
  float4 b = *(const float4*)(b2 + ((i4 & 255) * 4));
  float4 v;
  v.x = a.x + (bf2f(q0u.x) + bf2f(q1u.x)) + (bf2f(q2u.x) + bf2f(q3u.x)) + b.x;
  v.y = a.y + (bf2f(q0u.y) + bf2f(q1u.y)) + (bf2f(q2u.y) + bf2f(q3u.y)) + b.y;
  v.z = a.z + (bf2f(q0u.z) + bf2f(q1u.z)) + (bf2f(q2u.z) + bf2f(q3u.z)) + b.z;
  v.w = a.w + (bf2f(q0u.w) + bf2f(q1u.w)) + (bf2f(q2u.w) + bf2f(q3u.w)) + b.w;
  *(float4*)(out + idx) = v;
}

// ---------------------------------------------------------------------------
// Launch
// ---------------------------------------------------------------------------
extern "C" void kernel_launch(void* const* d_in, const int* in_sizes, int n_in,
                              void* d_out, int out_size, void* d_ws, size_t ws_size,
                              hipStream_t stream) {
  (void)in_sizes; (void)n_in; (void)out_size; (void)ws_size;
  const float* x    = (const float*)d_in[0];
  const int*   mask = (const int*)d_in[1];
  const float* wq   = (const float*)d_in[2];
  const float* bq   = (const float*)d_in[3];
  const float* wk   = (const float*)d_in[4];
  const float* bk   = (const float*)d_in[5];
  const float* wv   = (const float*)d_in[6];
  const float* bv   = (const float*)d_in[7];
  const float* wo   = (const float*)d_in[8];
  const float* bo   = (const float*)d_in[9];
  const float* w1   = (const float*)d_in[10];
  const float* b1   = (const float*)d_in[11];
  const float* w2   = (const float*)d_in[12];
  const float* b2   = (const float*)d_in[13];
  const float* ln1a = (const float*)d_in[14];
  const float* ln1b = (const float*)d_in[15];
  const float* ln2a = (const float*)d_in[16];
  const float* ln2b = (const float*)d_in[17];

  char* ws = (char*)d_ws;
  unsigned short* w_bf  = (unsigned short*)ws;            // 24 MB bf16 weights
  unsigned short* wq_bf = w_bf;
  unsigned short* wo_bf = w_bf + (3u << 20);
  unsigned short* w1_bf = w_bf + (4u << 20);
  unsigned short* w2_bf = w_bf + (8u << 20);
  unsigned short* h1    = (unsigned short*)(ws + (24u << 20));
  unsigned short* qbuf  = (unsigned short*)(ws + (32u << 20));
  unsigned short* kbuf  = (unsigned short*)(ws + (40u << 20));
  unsigned short* vtbuf = (unsigned short*)(ws + (48u << 20));
  unsigned short* attnb = (unsigned short*)(ws + (56u << 20));
  float*          x2    = (float*)(ws + (64u << 20));     // 16 MB
  unsigned short* h2    = (unsigned short*)(ws + (80u << 20));
  unsigned short* ffn1  = (unsigned short*)(ws + (88u << 20));  // 32 MB -> 120
  unsigned short* pp    = (unsigned short*)(ws + (88u << 20)); // proj partials
                                                          // (2x8MB, dead before
                                                          // ffn1 use)
  unsigned short* qq    = (unsigned short*)(ws + (24u << 20)); // ffn2 partials
                                                          // (4x8MB = 24..56MB;
                                                          // h1..attnb dead)
  float*          maskf = (float*)(ws + (120u << 20));    // 16 KB

  prep_kernel<<<MROWS + 1024, 256, 0, stream>>>(
      x, ln1a, ln1b, h1, wq, wk, wv, wo, w1, w2, mask, w_bf, maskf);
  gemm256_qkv<<<dim3(4, 16, 3), 512, 0, stream>>>(
      h1, wq_bf, bq, bk, bv, qbuf, vtbuf);
  attn_kernel<<<dim3(32, 16), 512, 0, stream>>>(qbuf, kbuf, vtbuf, maskf, attnb);
  gemm_bt<MODE_PARTIAL><<<dim3(8, 32, 2), 256, 0, stream>>>(
      attnb, wo_bf, nullptr, (void*)pp, MROWS, D_MODEL, 512);
  proj_ln2_kernel<<<MROWS, 256, 0, stream>>>(
      x, pp, pp + (size_t)MROWS * D_MODEL, bo, ln2a, ln2b, x2, h2);
  gemm256<1><<<dim3(16, 16), 512, 0, stream>>>(
      h2, w1_bf, b1, ffn1, MROWS, DFF, D_MODEL);
  gemm256<0><<<dim3(4, 16, 4), 512, 0, stream>>>(
      ffn1, w2_bf, nullptr, qq, MROWS, D_MODEL, 1024);
  ffn2_add_kernel<<<4096, 256, 0, stream>>>(x2, qq, b2, (float*)d_out);
}

// Round 22
// 238.818 us; speedup vs baseline: 1.0270x; 1.0075x over previous
//
#include <hip/hip_runtime.h>
#include <cstdint>
#include <cstddef>

// ---------------------------------------------------------------------------
// Types / helpers
// ---------------------------------------------------------------------------
typedef short bf16x8 __attribute__((ext_vector_type(8)));
typedef short bf16x4 __attribute__((ext_vector_type(4)));
typedef float f32x4 __attribute__((ext_vector_type(4)));

#define D_MODEL 1024
#define SEQ     2048
#define NBATCH  2
#define NH      16
#define DKH     64
#define DFF     4096
#define MROWS   (NBATCH * SEQ)   // 4096

#if defined(__HIP_DEVICE_COMPILE__)
#if __has_builtin(__builtin_amdgcn_mfma_f32_16x16x16bf16_1k)
#define MFMA16(a, b, c) __builtin_amdgcn_mfma_f32_16x16x16bf16_1k(a, b, c, 0, 0, 0)
#else
#define MFMA16(a, b, c) __builtin_amdgcn_mfma_f32_16x16x16_bf16(a, b, c, 0, 0, 0)
#endif
#if __has_builtin(__builtin_amdgcn_exp2f)
#define EXP2(x) __builtin_amdgcn_exp2f(x)
#else
#define EXP2(x) exp2f(x)
#endif
#else
__device__ __host__ static inline f32x4 MFMA16(bf16x4, bf16x4, f32x4 c) {
  return c;
}
#define EXP2(x) exp2f(x)
#endif

__device__ __forceinline__ unsigned short f2bf(float f) {
  unsigned u = __builtin_bit_cast(unsigned, f);
  u += 0x7fffu + ((u >> 16) & 1u);          // round-to-nearest-even
  return (unsigned short)(u >> 16);
}
__device__ __forceinline__ float bf2f(unsigned short u) {
  return __builtin_bit_cast(float, (unsigned)u << 16);
}
__device__ __forceinline__ unsigned packbf2(float lo, float hi) {
  unsigned r;
  asm("v_cvt_pk_bf16_f32 %0, %1, %2" : "=v"(r) : "v"(lo), "v"(hi));
  return r;
}
__device__ __forceinline__ void gload_lds16(const void* g, void* l) {
  __builtin_amdgcn_global_load_lds(
      (const __attribute__((address_space(1))) unsigned*)g,
      (__attribute__((address_space(3))) unsigned*)l, 16, 0, 0);
}

// ---------------------------------------------------------------------------
// prep: blocks <4096 do LN1 (one row each, torch semantics); blocks >=4096 do
// weight cast f32->bf16 (dst: [wq 1M][wk 1M][wv 1M][wo 1M][w1 4M][w2 4M]) and
// mask -> float addend (0/-1e9).
// ---------------------------------------------------------------------------
__global__ __launch_bounds__(256) void prep_kernel(
    const float* __restrict__ x, const float* __restrict__ alpha,
    const float* __restrict__ beta, unsigned short* __restrict__ h1,
    const float* __restrict__ wq, const float* __restrict__ wk,
    const float* __restrict__ wv, const float* __restrict__ wo,
    const float* __restrict__ w1, const float* __restrict__ w2,
    const int* __restrict__ mask, unsigned short* __restrict__ dst,
    float* __restrict__ maskf) {
  const int t = threadIdx.x;
  if (blockIdx.x < MROWS) {
    // ---- LayerNorm row ----
    const int row = blockIdx.x;
    float4 v = *(const float4*)(x + (size_t)row * D_MODEL + t * 4);
    float s = v.x + v.y + v.z + v.w;
#pragma unroll
    for (int o = 1; o < 64; o <<= 1) s += __shfl_xor(s, o, 64);
    __shared__ float red[8];
    if ((t & 63) == 0) red[t >> 6] = s;
    __syncthreads();
    float mean = (red[0] + red[1] + red[2] + red[3]) * (1.f / D_MODEL);
    float dx = v.x - mean, dy = v.y - mean, dz = v.z - mean, dw = v.w - mean;
    float sq = dx * dx + dy * dy + dz * dz + dw * dw;
#pragma unroll
    for (int o = 1; o < 64; o <<= 1) sq += __shfl_xor(sq, o, 64);
    if ((t & 63) == 0) red[4 + (t >> 6)] = sq;
    __syncthreads();
    float var = (red[4] + red[5] + red[6] + red[7]) * (1.f / (D_MODEL - 1));
    float inv = 1.f / (sqrtf(var) + 1e-6f);
    float4 a = *(const float4*)(alpha + t * 4);
    float4 be = *(const float4*)(beta + t * 4);
    ushort4 o4;
    o4.x = f2bf(a.x * dx * inv + be.x);
    o4.y = f2bf(a.y * dy * inv + be.y);
    o4.z = f2bf(a.z * dz * inv + be.z);
    o4.w = f2bf(a.w * dw * inv + be.w);
    *(ushort4*)(h1 + (size_t)row * D_MODEL + t * 4) = o4;
  } else {
    // ---- weight cast + mask convert ----
    const int TOT4 = (12 << 20) >> 2;
    const int gid = (blockIdx.x - MROWS) * 256 + t;
    for (int i4 = gid; i4 < TOT4; i4 += 1024 * 256) {
      int i = i4 << 2;
      const float* src;
      int off;
      if (i < (4 << 20)) {
        src = (i < (2 << 20)) ? ((i < (1 << 20)) ? wq : wk)
                              : ((i < (3 << 20)) ? wv : wo);
        off = i & ((1 << 20) - 1);
      } else if (i < (8 << 20)) { src = w1; off = i - (4 << 20); }
      else                      { src = w2; off = i - (8 << 20); }
      float4 v = *(const float4*)(src + off);
      ushort4 o;
      o.x = f2bf(v.x); o.y = f2bf(v.y); o.z = f2bf(v.z); o.w = f2bf(v.w);
      *(ushort4*)(dst + i) = o;
    }
    if (gid < (NBATCH * SEQ / 4)) {
      int4 m = ((const int4*)mask)[gid];
      float4 f;
      f.x = (m.x == 0) ? -1e9f : 0.f;
      f.y = (m.y == 0) ? -1e9f : 0.f;
      f.z = (m.z == 0) ? -1e9f : 0.f;
      f.w = (m.w == 0) ? -1e9f : 0.f;
      ((float4*)maskf)[gid] = f;
    }
  }
}

// ---------------------------------------------------------------------------
// GEMM core macros (128x128 tile, BK=32, 4 waves 2x2, double-buffered LDS)
// ---------------------------------------------------------------------------
#define GEMM_STAGE(A_, W_, LD_, koff_, kt_, buf_)                                  \
  {                                                                                \
    int ke_ = (koff_) + (kt_) * 32;                                                \
    gload_lds16(A_ + (size_t)(m0 + srow) * (LD_) + ke_ + sce, &lds[(buf_)][0][t * 8]);        \
    gload_lds16(A_ + (size_t)(m0 + 64 + srow) * (LD_) + ke_ + sce, &lds[(buf_)][0][2048 + t * 8]); \
    gload_lds16(W_ + (size_t)(n0 + srow) * (LD_) + ke_ + sce, &lds[(buf_)][1][t * 8]);        \
    gload_lds16(W_ + (size_t)(n0 + 64 + srow) * (LD_) + ke_ + sce, &lds[(buf_)][1][2048 + t * 8]); \
  }

#define GEMM_MAINLOOP(A_, W_, LD_, K_, koff_)                                      \
  GEMM_STAGE(A_, W_, LD_, koff_, 0, 0);                                            \
  for (int kt = 0; kt < ((K_) >> 5); ++kt) {                                       \
    __syncthreads();                                                               \
    if (kt + 1 < ((K_) >> 5)) GEMM_STAGE(A_, W_, LD_, koff_, kt + 1, (kt + 1) & 1); \
    const unsigned short* la = lds[kt & 1][0];                                     \
    const unsigned short* lb = lds[kt & 1][1];                                     \
    bf16x8 af[4], bfr[4];                                                          \
    _Pragma("unroll") for (int i = 0; i < 4; i++) {                                \
      af[i]  = *(const bf16x8*)&la[(wm + i * 16 + c) * 32 + g * 8];                \
      bfr[i] = *(const bf16x8*)&lb[(wn + i * 16 + c) * 32 + g * 8];                \
    }                                                                              \
    _Pragma("unroll") for (int mi = 0; mi < 4; mi++)                               \
      _Pragma("unroll") for (int ni = 0; ni < 4; ni++)                             \
        acc[mi][ni] = __builtin_amdgcn_mfma_f32_16x16x32_bf16(af[mi], bfr[ni],     \
                                                              acc[mi][ni], 0, 0, 0); \
  }

enum { MODE_BF16 = 0, MODE_RELU = 2, MODE_PARTIAL = 4 };

template <int MODE>
__global__ __launch_bounds__(256) void gemm_bt(
    const unsigned short* __restrict__ A, const unsigned short* __restrict__ W,
    const float* __restrict__ bias, void* __restrict__ outp, int M, int N, int K) {
  __shared__ unsigned short lds[2][2][128 * 32];
  const int t = threadIdx.x;
  const int lane = t & 63, wid = t >> 6;
  const int g = lane >> 4, c = lane & 15;
  const int m0 = blockIdx.y * 128, n0 = blockIdx.x * 128;
  const int wm = (wid >> 1) * 64, wn = (wid & 1) * 64;
  const int srow = t >> 2, sce = (t & 3) * 8;
  const int ldk = K * gridDim.z;
  const int koff = blockIdx.z * K;

  f32x4 zero = {0.f, 0.f, 0.f, 0.f};
  f32x4 acc[4][4];
#pragma unroll
  for (int i = 0; i < 4; i++)
#pragma unroll
    for (int j = 0; j < 4; j++) acc[i][j] = zero;

  GEMM_MAINLOOP(A, W, ldk, K, koff);

  float bv[4];
#pragma unroll
  for (int ni = 0; ni < 4; ni++)
    bv[ni] = (MODE == MODE_PARTIAL) ? 0.f : bias[n0 + wn + ni * 16 + c];

  unsigned short* po = (unsigned short*)outp +
                       ((MODE == MODE_PARTIAL) ? (size_t)blockIdx.z * M * N : 0);

#pragma unroll
  for (int mi = 0; mi < 4; mi++) {
#pragma unroll
    for (int ni = 0; ni < 4; ni++) {
      const int mb = m0 + wm + mi * 16 + g * 4;
      const int n = n0 + wn + ni * 16 + c;
#pragma unroll
      for (int r = 0; r < 4; r++) {
        const int m = mb + r;
        float v = acc[mi][ni][r] + bv[ni];
        if (MODE == MODE_RELU) v = fmaxf(v, 0.f);
        po[(size_t)m * N + n] = f2bf(v);   // bf16 partials / outputs
      }
    }
  }
}

// ---------------------------------------------------------------------------
// 256x256-tile 4-phase GEMM main-loop macro, fine-grained interleave
// (m201-style). Per K-tile T: {issue 2 gloads of T+1 -> vmcnt(2) -> barrier ->
// 4 x phase[8 ds_read_b128 ; 2 more gloads ; barrier ; setprio+16 MFMA ;
// barrier]}.  Requires locals: A, W, ldk, koff, m0, n0, srow, sch, wr, wc,
// g, c, Atile, Btile, acc, NT.
// ---------------------------------------------------------------------------
#define G256_STAGE1(T_, b_, i_)                                                    \
  {                                                                               \
    const int r_ = srow + (i_) * 64;                                              \
    gload_lds16(A + (size_t)(m0 + r_) * ldk + koff + (T_) * 64 +                  \
                    ((sch ^ (r_ & 7)) << 3),                                      \
                &Atile[b_][r_ * 64 + sch * 8]);                                   \
    gload_lds16(W + (size_t)(n0 + r_) * ldk + koff + (T_) * 64 +                  \
                    ((sch ^ (r_ & 7)) << 3),                                      \
                &Btile[b_][r_ * 64 + sch * 8]);                                   \
  }

#define G256_MAINLOOP()                                                           \
  G256_STAGE1(0, 0, 0); G256_STAGE1(0, 0, 1);                                     \
  G256_STAGE1(0, 0, 2); G256_STAGE1(0, 0, 3);                                     \
  for (int T = 0; T < NT; ++T) {                                                  \
    const int b = T & 1;                                                          \
    const bool more = (T + 1 < NT);                                               \
    if (more) {                                                                   \
      G256_STAGE1(T + 1, b ^ 1, 0);                                               \
      asm volatile("s_waitcnt vmcnt(2)" ::: "memory");                            \
    } else {                                                                      \
      asm volatile("s_waitcnt vmcnt(0)" ::: "memory");                            \
    }                                                                             \
    __builtin_amdgcn_sched_barrier(0);                                            \
    __builtin_amdgcn_s_barrier();                                                 \
    _Pragma("unroll") for (int q = 0; q < 4; ++q) {                               \
      const int kk = q >> 1, mh = (q & 1) * 4;                                    \
      bf16x8 af[4], bfq[4];                                                       \
      _Pragma("unroll") for (int j = 0; j < 4; j++) {                             \
        const int ar = wr * 128 + (mh + j) * 16 + c;                              \
        const int br = wc * 64 + j * 16 + c;                                      \
        const int sl = ((kk * 4 + g) ^ (c & 7)) << 3;                             \
        af[j] = *(const bf16x8*)&Atile[b][ar * 64 + sl];                          \
        bfq[j] = *(const bf16x8*)&Btile[b][br * 64 + sl];                         \
      }                                                                           \
      if (q > 0 && more) G256_STAGE1(T + 1, b ^ 1, q);                            \
      __builtin_amdgcn_s_barrier();                                               \
      __builtin_amdgcn_s_setprio(1);                                              \
      _Pragma("unroll") for (int j = 0; j < 4; j++)                               \
        _Pragma("unroll") for (int n = 0; n < 4; n++)                             \
          acc[mh + j][n] = __builtin_amdgcn_mfma_f32_16x16x32_bf16(               \
              af[j], bfq[n], acc[mh + j][n], 0, 0, 0);                            \
      __builtin_amdgcn_s_setprio(0);                                              \
      __builtin_amdgcn_s_barrier();                                               \
    }                                                                             \
  }

// FFN1 (RELU=1, full K) / FFN2 (RELU=0, bf16 partials, split-K via blockIdx.z)
template <int RELU>
__global__ __launch_bounds__(512, 2) void gemm256(
    const unsigned short* __restrict__ A, const unsigned short* __restrict__ W,
    const float* __restrict__ bias, unsigned short* __restrict__ out,
    int M, int N, int KS) {
  __shared__ unsigned short Atile[2][256 * 64];
  __shared__ unsigned short Btile[2][256 * 64];
  const int t = threadIdx.x, lane = t & 63, wid = t >> 6;
  const int g = lane >> 4, c = lane & 15;
  const int wr = wid >> 2, wc = wid & 3;          // 2x4 wave grid
  const int m0 = blockIdx.y * 256, n0 = blockIdx.x * 256;
  const int srow = t >> 3, sch = t & 7;           // staging row / 16B-chunk
  const int NT = KS >> 6;
  const int ldk = KS * gridDim.z;
  const int koff = blockIdx.z * KS;
  (void)M;

  f32x4 zero = {0.f, 0.f, 0.f, 0.f};
  f32x4 acc[8][4];
#pragma unroll
  for (int i = 0; i < 8; i++)
#pragma unroll
    for (int j = 0; j < 4; j++) acc[i][j] = zero;

  G256_MAINLOOP();

  float bv[4];
#pragma unroll
  for (int ni = 0; ni < 4; ni++)
    bv[ni] = RELU ? bias[n0 + wc * 64 + ni * 16 + c] : 0.f;

  unsigned short* po = out + (RELU ? 0 : (size_t)blockIdx.z * M * N);

#pragma unroll
  for (int mi = 0; mi < 8; mi++) {
#pragma unroll
    for (int ni = 0; ni < 4; ni++) {
      const int mb = m0 + wr * 128 + mi * 16 + g * 4;
      const int n = n0 + wc * 64 + ni * 16 + c;
#pragma unroll
      for (int r = 0; r < 4; r++) {
        float v = acc[mi][ni][r] + bv[ni];
        if (RELU) v = fmaxf(v, 0.f);
        po[(size_t)(mb + r) * N + n] = f2bf(v);
      }
    }
  }
}

// QKV on the 256-tile structure: grid (4, 16, 3); blockIdx.z selects weight.
// Q written pre-scaled by 1/8; K plain; V written transposed Vt (B,H,dk,S).
__global__ __launch_bounds__(512, 2) void gemm256_qkv(
    const unsigned short* __restrict__ A, const unsigned short* __restrict__ Wbase,
    const float* __restrict__ bq, const float* __restrict__ bk,
    const float* __restrict__ bv_, unsigned short* __restrict__ qkout,
    unsigned short* __restrict__ vtout) {
  __shared__ unsigned short Atile[2][256 * 64];
  __shared__ unsigned short Btile[2][256 * 64];
  const int t = threadIdx.x, lane = t & 63, wid = t >> 6;
  const int g = lane >> 4, c = lane & 15;
  const int wr = wid >> 2, wc = wid & 3;
  const int m0 = blockIdx.y * 256, n0 = blockIdx.x * 256;
  const int srow = t >> 3, sch = t & 7;
  const int NT = 16;                              // K = 1024
  const int ldk = 1024, koff = 0;
  const int wsel = blockIdx.z;
  const unsigned short* W = Wbase + ((size_t)wsel << 20);
  const float* bias = (wsel == 0) ? bq : (wsel == 1) ? bk : bv_;

  f32x4 zero = {0.f, 0.f, 0.f, 0.f};
  f32x4 acc[8][4];
#pragma unroll
  for (int i = 0; i < 8; i++)
#pragma unroll
    for (int j = 0; j < 4; j++) acc[i][j] = zero;

  G256_MAINLOOP();

  float bvv[4];
#pragma unroll
  for (int ni = 0; ni < 4; ni++) bvv[ni] = bias[n0 + wc * 64 + ni * 16 + c];
  const float qsc = (wsel == 0) ? 0.125f : 1.f;

  if (wsel < 2) {
    unsigned short* outp = qkout + ((size_t)wsel << 22);  // q then k
#pragma unroll
    for (int mi = 0; mi < 8; mi++) {
#pragma unroll
      for (int ni = 0; ni < 4; ni++) {
        const int mb = m0 + wr * 128 + mi * 16 + g * 4;
        const int n = n0 + wc * 64 + ni * 16 + c;
#pragma unroll
        for (int r = 0; r < 4; r++)
          outp[(size_t)(mb + r) * 1024 + n] = f2bf((acc[mi][ni][r] + bvv[ni]) * qsc);
      }
    }
  } else {
    // V^T: vtout[(b*1024 + n)*2048 + s]; mb%4==0 so 4 r-values share b
#pragma unroll
    for (int mi = 0; mi < 8; mi++) {
#pragma unroll
      for (int ni = 0; ni < 4; ni++) {
        const int mb = m0 + wr * 128 + mi * 16 + g * 4;
        const int n = n0 + wc * 64 + ni * 16 + c;
        const int b = mb >> 11, s2 = mb & 2047;
        ushort4 o4;
        o4.x = f2bf(acc[mi][ni][0] + bvv[ni]);
        o4.y = f2bf(acc[mi][ni][1] + bvv[ni]);
        o4.z = f2bf(acc[mi][ni][2] + bvv[ni]);
        o4.w = f2bf(acc[mi][ni][3] + bvv[ni]);
        *(ushort4*)(vtout + ((size_t)(b * 1024 + n)) * 2048 + s2) = o4;
      }
    }
  }
}

// ---------------------------------------------------------------------------
// Flash attention, 8-wave blocks, KV tile = 128 (16 iterations). grid =
// (B*H, S/128): XCD = bh%8. Tree-reduced softmax max/sum (depth 5 vs 31).
// ---------------------------------------------------------------------------
#define VSWZ(ch_, r_) (((ch_) & 8) | (((ch_) ^ ((r_) & 7)) & 7))

#define ATTN_STAGE128(base_, buf_)                                                  \
  {                                                                                 \
    const int kr0_ = t >> 3, kr1_ = 64 + (t >> 3), kch_ = t & 7;                    \
    gload_lds16(Kb + (size_t)((base_) + kr0_) * D_MODEL +                           \
                    ((kch_ ^ (kr0_ & 7)) << 3), &Klds[buf_][t * 8]);                \
    gload_lds16(Kb + (size_t)((base_) + kr1_) * D_MODEL +                           \
                    ((kch_ ^ (kr1_ & 7)) << 3), &Klds[buf_][4096 + t * 8]);         \
    const int vr0_ = t >> 4, vr1_ = 32 + (t >> 4), vch_ = t & 15;                   \
    gload_lds16(Vb + (size_t)vr0_ * SEQ + (base_) + (VSWZ(vch_, vr0_) << 3),        \
                &Vlds[buf_][t * 8]);                                                \
    gload_lds16(Vb + (size_t)vr1_ * SEQ + (base_) + (VSWZ(vch_, vr1_) << 3),        \
                &Vlds[buf_][4096 + t * 8]);                                         \
  }

__global__ __launch_bounds__(512, 4) void attn_kernel(
    const unsigned short* __restrict__ Q, const unsigned short* __restrict__ Kmat,
    const unsigned short* __restrict__ Vt, const float* __restrict__ maskf,
    unsigned short* __restrict__ O) {
  __shared__ unsigned short Klds[2][128 * 64];
  __shared__ unsigned short Vlds[2][64 * 128];
  __shared__ float masklds[SEQ];
  const int t = threadIdx.x, lane = t & 63, wid = t >> 6;
  const int g = lane >> 4, c = lane & 15;
  const int bh = blockIdx.x, qt = blockIdx.y;   // bh on x => XCD = bh%8
  const int b = bh >> 4, h = bh & 15;
  const int q0 = qt * 128 + wid * 16;           // 8 waves x 16 q-rows

  const unsigned short* Qb = Q + (size_t)b * SEQ * D_MODEL + h * DKH;
  const unsigned short* Kb = Kmat + (size_t)b * SEQ * D_MODEL + h * DKH;
  const unsigned short* Vb = Vt + (size_t)bh * DKH * SEQ;
  const float* mbf = maskf + b * SEQ;

  bf16x8 qf[2];
#pragma unroll
  for (int kd = 0; kd < 2; kd++)
    qf[kd] = *(const bf16x8*)&Qb[(size_t)(q0 + c) * D_MODEL + kd * 32 + g * 8];

  f32x4 zero = {0.f, 0.f, 0.f, 0.f};
  f32x4 of[4];
#pragma unroll
  for (int j = 0; j < 4; j++) of[j] = zero;
  float mrun = -1e30f, lrun = 0.f;

  // stage mask addends (2048 floats = 8 KB, one gload/thread) + first K/V tile
  gload_lds16(mbf + t * 4, &masklds[t * 4]);
  ATTN_STAGE128(0, 0);

  for (int kv = 0; kv < 16; ++kv) {
    const int buf = kv & 1;
    const int base = kv * 128;
    __syncthreads();                        // drains this buf's gloads
    if (kv < 15) ATTN_STAGE128(base + 128, buf ^ 1);

    // --- QK^T: S^T[kv 128][q 16] per wave; K fragments loaded per-nb ---
    f32x4 sf[8];
    __builtin_amdgcn_s_setprio(1);
#pragma unroll
    for (int nb = 0; nb < 8; nb++) {
      const int row = nb * 16 + c;
      bf16x8 kf0 = *(const bf16x8*)&Klds[buf][row * 64 + ((g ^ (c & 7)) << 3)];
      bf16x8 kf1 = *(const bf16x8*)&Klds[buf][row * 64 + (((4 + g) ^ (c & 7)) << 3)];
      f32x4 s = zero;
      s = __builtin_amdgcn_mfma_f32_16x16x32_bf16(kf0, qf[0], s, 0, 0, 0);
      s = __builtin_amdgcn_mfma_f32_16x16x32_bf16(kf1, qf[1], s, 0, 0, 0);
      sf[nb] = s;
    }
    __builtin_amdgcn_s_setprio(0);

    // additive mask (pre-converted 0/-1e9)
#pragma unroll
    for (int nb = 0; nb < 8; nb++) {
      float4 ma = *(const float4*)&masklds[base + nb * 16 + g * 4];
      sf[nb][0] += ma.x; sf[nb][1] += ma.y; sf[nb][2] += ma.z; sf[nb][3] += ma.w;
    }

    // online softmax with defer-max (THR=8); tree-reduced max (depth 5)
    float pmn[8];
#pragma unroll
    for (int nb = 0; nb < 8; nb++)
      pmn[nb] = fmaxf(fmaxf(sf[nb][0], sf[nb][1]), fmaxf(sf[nb][2], sf[nb][3]));
    float pm = fmaxf(fmaxf(fmaxf(pmn[0], pmn[1]), fmaxf(pmn[2], pmn[3])),
                     fmaxf(fmaxf(pmn[4], pmn[5]), fmaxf(pmn[6], pmn[7])));
    pm = fmaxf(pm, __shfl_xor(pm, 16, 64));
    pm = fmaxf(pm, __shfl_xor(pm, 32, 64));
    if (!__all(pm <= mrun + 8.f)) {
      float mnew = fmaxf(mrun, pm);
      float fsc = EXP2((mrun - mnew) * 1.44269504f);
      lrun *= fsc;
#pragma unroll
      for (int dkb = 0; dkb < 4; dkb++) of[dkb] *= fsc;
      mrun = mnew;
    }
    const float mb2 = mrun * 1.44269504f;
    float psn[8];
#pragma unroll
    for (int nb = 0; nb < 8; nb++) {
      float p0 = EXP2(fmaf(sf[nb][0], 1.44269504f, -mb2));
      float p1 = EXP2(fmaf(sf[nb][1], 1.44269504f, -mb2));
      float p2 = EXP2(fmaf(sf[nb][2], 1.44269504f, -mb2));
      float p3 = EXP2(fmaf(sf[nb][3], 1.44269504f, -mb2));
      sf[nb][0] = p0; sf[nb][1] = p1; sf[nb][2] = p2; sf[nb][3] = p3;
      psn[nb] = (p0 + p1) + (p2 + p3);
    }
    lrun += ((psn[0] + psn[1]) + (psn[2] + psn[3])) +
            ((psn[4] + psn[5]) + (psn[6] + psn[7]));

    // --- PV: of[dkb] += V^T-frag x P^T-frag per 16-kv block nb (0..7).
    // logical chunk q = 2nb + (g>>1) in [0,16); stored chunk = VSWZ(q, c&7).
#pragma unroll
    for (int nb = 0; nb < 8; nb++) {
      const int qc = 2 * nb + (g >> 1);
      bf16x4 vv[4];
#pragma unroll
      for (int dkb = 0; dkb < 4; dkb++) {
        const int row = dkb * 16 + c;
        const int vbyte = row * 256 + (VSWZ(qc, c) << 4) + ((g & 1) << 3);
        vv[dkb] = *(const bf16x4*)((const char*)Vlds[buf] + vbyte);
      }
      unsigned plo = packbf2(sf[nb][0], sf[nb][1]);
      unsigned phi = packbf2(sf[nb][2], sf[nb][3]);
      unsigned long long uu = (unsigned long long)plo |
                              ((unsigned long long)phi << 32);
      bf16x4 pf = __builtin_bit_cast(bf16x4, uu);
      __builtin_amdgcn_s_setprio(1);
#pragma unroll
      for (int dkb = 0; dkb < 4; dkb++)
        of[dkb] = MFMA16(vv[dkb], pf, of[dkb]);
      __builtin_amdgcn_s_setprio(0);
    }
  }

  float lt = lrun;
  lt += __shfl_xor(lt, 16, 64);
  lt += __shfl_xor(lt, 32, 64);
  float inv = 1.f / lt;
#pragma unroll
  for (int dkb = 0; dkb < 4; dkb++) {
    ushort4 o4;
    o4.x = f2bf(of[dkb][0] * inv);
    o4.y = f2bf(of[dkb][1] * inv);
    o4.z = f2bf(of[dkb][2] * inv);
    o4.w = f2bf(of[dkb][3] * inv);
    *(ushort4*)&O[(size_t)(b * SEQ + q0 + c) * D_MODEL + h * DKH + dkb * 16 +
                  g * 4] = o4;
  }
}

// ---------------------------------------------------------------------------
// Fused epilogues (bf16 split-K partials)
// proj_ln2: x2 = x + P0 + P1 + bo;  h2 = LN2(x2).  one block per row.
// ---------------------------------------------------------------------------
__global__ __launch_bounds__(256) void proj_ln2_kernel(
    const float* __restrict__ x, const unsigned short* __restrict__ P0,
    const unsigned short* __restrict__ P1, const float* __restrict__ bo,
    const float* __restrict__ alpha, const float* __restrict__ beta,
    float* __restrict__ x2, unsigned short* __restrict__ h2) {
  const int row = blockIdx.x;
  const int t = threadIdx.x;
  const size_t idx = (size_t)row * D_MODEL + t * 4;
  float4 xv = *(const float4*)(x + idx);
  ushort4 p0u = *(const ushort4*)(P0 + idx);
  ushort4 p1u = *(const ushort4*)(P1 + idx);
  float4 bo4 = *(const float4*)(bo + t * 4);
  float4 v;
  v.x = xv.x + bf2f(p0u.x) + bf2f(p1u.x) + bo4.x;
  v.y = xv.y + bf2f(p0u.y) + bf2f(p1u.y) + bo4.y;
  v.z = xv.z + bf2f(p0u.z) + bf2f(p1u.z) + bo4.z;
  v.w = xv.w + bf2f(p0u.w) + bf2f(p1u.w) + bo4.w;
  *(float4*)(x2 + idx) = v;

  float s = v.x + v.y + v.z + v.w;
#pragma unroll
  for (int o = 1; o < 64; o <<= 1) s += __shfl_xor(s, o, 64);
  __shared__ float red[8];
  if ((t & 63) == 0) red[t >> 6] = s;
  __syncthreads();
  float mean = (red[0] + red[1] + red[2] + red[3]) * (1.f / D_MODEL);
  float dx = v.x - mean, dy = v.y - mean, dz = v.z - mean, dw = v.w - mean;
  float sq = dx * dx + dy * dy + dz * dz + dw * dw;
#pragma unroll
  for (int o = 1; o < 64; o <<= 1) sq += __shfl_xor(sq, o, 64);
  if ((t & 63) == 0) red[4 + (t >> 6)] = sq;
  __syncthreads();
  float var = (red[4] + red[5] + red[6] + red[7]) * (1.f / (D_MODEL - 1));
  float inv = 1.f / (sqrtf(var) + 1e-6f);
  float4 a = *(const float4*)(alpha + t * 4);
  float4 be = *(const float4*)(beta + t * 4);
  ushort4 o4;
  o4.x = f2bf(a.x * dx * inv + be.x);
  o4.y = f2bf(a.y * dy * inv + be.y);
  o4.z = f2bf(a.z * dz * inv + be.z);
  o4.w = f2bf(a.w * dw * inv + be.w);
  *(ushort4*)(h2 + idx) = o4;
}

// ffn2_add: out = x2 + Q0+Q1+Q2+Q3 + b2  (final output, f32; bf16 partials x4)
__global__ __launch_bounds__(256) void ffn2_add_kernel(
    const float* __restrict__ x2, const unsigned short* __restrict__ Q0,
    const float* __restrict__ b2, float* __restrict__ out) {
  const int i4 = blockIdx.x * blockDim.x + threadIdx.x;  // 1M float4s
  const size_t idx = (size_t)i4 * 4;
  const size_t stride = (size_t)MROWS * D_MODEL;
  float4 a = *(const float4*)(x2 + idx);
  ushort4 q0u = *(const ushort4*)(Q0 + idx);
  ushort4 q1u = *(const ushort4*)(Q0 + stride + idx);
  ushort4 q2u = *(const ushort4*)(Q0 + 2 * stride + idx);
  ushort4 q3u = *(const ushort4*)(Q0 + 3 * stride + idx);
  float4 b = *(const float4*)(b2 + ((i4 & 255) * 4));
  float4 v;
  v.x = a.x + (bf2f(q0u.x) + bf2f(q1u.x)) + (bf2f(q2u.x) + bf2f(q3u.x)) + b.x;
  v.y = a.y + (bf2f(q0u.y) + bf2f(q1u.y)) + (bf2f(q2u.y) + bf2f(q3u.y)) + b.y;
  v.z = a.z + (bf2f(q0u.z) + bf2f(q1u.z)) + (bf2f(q2u.z) + bf2f(q3u.z)) + b.z;
  v.w = a.w + (bf2f(q0u.w) + bf2f(q1u.w)) + (bf2f(q2u.w) + bf2f(q3u.w)) + b.w;
  *(float4*)(out + idx) = v;
}

// ---------------------------------------------------------------------------
// Launch
// ---------------------------------------------------------------------------
extern "C" void kernel_launch(void* const* d_in, const int* in_sizes, int n_in,
                              void* d_out, int out_size, void* d_ws, size_t ws_size,
                              hipStream_t stream) {
  (void)in_sizes; (void)n_in; (void)out_size; (void)ws_size;
  const float* x    = (const float*)d_in[0];
  const int*   mask = (const int*)d_in[1];
  const float* wq   = (const float*)d_in[2];
  const float* bq   = (const float*)d_in[3];
  const float* wk   = (const float*)d_in[4];
  const float* bk   = (const float*)d_in[5];
  const float* wv   = (const float*)d_in[6];
  const float* bv   = (const float*)d_in[7];
  const float* wo   = (const float*)d_in[8];
  const float* bo   = (const float*)d_in[9];
  const float* w1   = (const float*)d_in[10];
  const float* b1   = (const float*)d_in[11];
  const float* w2   = (const float*)d_in[12];
  const float* b2   = (const float*)d_in[13];
  const float* ln1a = (const float*)d_in[14];
  const float* ln1b = (const float*)d_in[15];
  const float* ln2a = (const float*)d_in[16];
  const float* ln2b = (const float*)d_in[17];

  char* ws = (char*)d_ws;
  unsigned short* w_bf  = (unsigned short*)ws;            // 24 MB bf16 weights
  unsigned short* wq_bf = w_bf;
  unsigned short* wo_bf = w_bf + (3u << 20);
  unsigned short* w1_bf = w_bf + (4u << 20);
  unsigned short* w2_bf = w_bf + (8u << 20);
  unsigned short* h1    = (unsigned short*)(ws + (24u << 20));
  unsigned short* qbuf  = (unsigned short*)(ws + (32u << 20));
  unsigned short* kbuf  = (unsigned short*)(ws + (40u << 20));
  unsigned short* vtbuf = (unsigned short*)(ws + (48u << 20));
  unsigned short* attnb = (unsigned short*)(ws + (56u << 20));
  float*          x2    = (float*)(ws + (64u << 20));     // 16 MB
  unsigned short* h2    = (unsigned short*)(ws + (80u << 20));
  unsigned short* ffn1  = (unsigned short*)(ws + (88u << 20));  // 32 MB -> 120
  unsigned short* pp    = (unsigned short*)(ws + (88u << 20)); // proj partials
                                                          // (2x8MB, dead before
                                                          // ffn1 use)
  unsigned short* qq    = (unsigned short*)(ws + (24u << 20)); // ffn2 partials
                                                          // (4x8MB = 24..56MB;
                                                          // h1..attnb dead)
  float*          maskf = (float*)(ws + (120u << 20));    // 16 KB

  prep_kernel<<<MROWS + 1024, 256, 0, stream>>>(
      x, ln1a, ln1b, h1, wq, wk, wv, wo, w1, w2, mask, w_bf, maskf);
  gemm256_qkv<<<dim3(4, 16, 3), 512, 0, stream>>>(
      h1, wq_bf, bq, bk, bv, qbuf, vtbuf);
  attn_kernel<<<dim3(32, 16), 512, 0, stream>>>(qbuf, kbuf, vtbuf, maskf, attnb);
  gemm_bt<MODE_PARTIAL><<<dim3(8, 32, 2), 256, 0, stream>>>(
      attnb, wo_bf, nullptr, (void*)pp, MROWS, D_MODEL, 512);
  proj_ln2_kernel<<<MROWS, 256, 0, stream>>>(
      x, pp, pp + (size_t)MROWS * D_MODEL, bo, ln2a, ln2b, x2, h2);
  gemm256<1><<<dim3(16, 16), 512, 0, stream>>>(
      h2, w1_bf, b1, ffn1, MROWS, DFF, D_MODEL);
  gemm256<0><<<dim3(4, 16, 4), 512, 0, stream>>>(
      ffn1, w2_bf, nullptr, qq, MROWS, D_MODEL, 1024);
  ffn2_add_kernel<<<4096, 256, 0, stream>>>(x2, qq, b2, (float*)d_out);
}